// Round 5
// baseline (13323.174 us; speedup 1.0000x reference)
//
#include <hip/hip_runtime.h>

// All tensors fp32 (per the reference: inputs, weights, outputs all float32).

// ---------------------------------------------------------------------------
// LDS-tiled direct conv1d ("implicit GEMM"). Block = 64 co x 64 t for one b.
// Threads 256 = 16tx(t) x 16ty(co); each thread 4co x 4t register tile.
// Per ci-chunk (CI channels): stage input span (GN+ReLU fused here) and
// weights [ci][k][64co] in LDS, then FMA from aligned LDS vectors.
//   TSTORE: write transposed [pos][co] layout (pre-VQ z).
//   VSTORE: float4 stores (dst 16B-aligned); else scalar stores.
// ---------------------------------------------------------------------------
template<int K, int S, bool GN, bool RESID, bool RELU_OUT, bool TSTORE, bool VSTORE>
__global__ __launch_bounds__(256) void convtile_k(
    const float* __restrict__ in, const float* __restrict__ w,
    const float* __restrict__ bias, float* __restrict__ out,
    const float* __restrict__ scale, const float* __restrict__ shift,
    const float* __restrict__ resid,
    int Cin, int Lin, int Lout, int pad, int Cout)
{
    constexpr int CI    = (K == 1) ? 32 : 16;   // ci chunk
    constexpr int SPAN  = 63 * S + K;           // staged input span per ci
    constexpr int SPANP = (SPAN + 3) & ~3;      // 16B-aligned row stride
    constexpr int WN    = 3 * S + K;            // per-thread window

    __shared__ float lin[CI * SPANP];
    __shared__ float lw[CI * K * 64];

    const int tid = threadIdx.x;
    const int tx = tid & 15, ty = tid >> 4;
    const int t0 = blockIdx.x * 64;
    const int o0 = blockIdx.y * 64;
    const int b  = blockIdx.z;

    float acc[4][4];
    #pragma unroll
    for (int c = 0; c < 4; ++c) {
        float bv = bias ? bias[o0 + 4 * ty + c] : 0.0f;
        #pragma unroll
        for (int u = 0; u < 4; ++u) acc[c][u] = bv;
    }

    const float* inb = in + (size_t)b * Cin * Lin;
    const int p0 = t0 * S - pad;

    for (int ci0 = 0; ci0 < Cin; ci0 += CI) {
        __syncthreads();
        // ---- stage input (coalesced; GN+ReLU fused; zero-fill OOB) ----
        for (int idx = tid; idx < CI * SPAN; idx += 256) {
            int ci = idx / SPAN, j = idx - ci * SPAN;
            int p = p0 + j;
            bool ok = (p >= 0) && (p < Lin);
            float v = ok ? inb[(size_t)(ci0 + ci) * Lin + p] : 0.0f;
            if (GN) {
                float sc = scale[b * Cin + ci0 + ci];
                float sh = shift[b * Cin + ci0 + ci];
                v = ok ? fmaxf(v * sc + sh, 0.0f) : 0.0f;
            }
            lin[ci * SPANP + j] = v;
        }
        // ---- stage weights -> [ci][k][co64] (LDS writes conflict-free) ----
        for (int idx = tid; idx < CI * K * 64; idx += 256) {
            int co = idx & 63;
            int r  = idx >> 6;
            int k  = r % K, ci = r / K;
            lw[idx] = w[(size_t)(o0 + co) * Cin * K + (size_t)(ci0 + ci) * K + k];
        }
        __syncthreads();

        for (int ci = 0; ci < CI; ++ci) {
            float win[WN];
            const float* lrow = &lin[ci * SPANP + 4 * S * tx];
            #pragma unroll
            for (int j = 0; j < WN; ++j) win[j] = lrow[j];
            #pragma unroll
            for (int k = 0; k < K; ++k) {
                const float4 wv = *(const float4*)&lw[(ci * K + k) * 64 + 4 * ty];
                #pragma unroll
                for (int u = 0; u < 4; ++u) {
                    float x = win[u * S + k];
                    acc[0][u] += x * wv.x;
                    acc[1][u] += x * wv.y;
                    acc[2][u] += x * wv.z;
                    acc[3][u] += x * wv.w;
                }
            }
        }
    }

    // ---- epilogue ----
    if (RESID) {
        #pragma unroll
        for (int c = 0; c < 4; ++c) {
            const float4 rv = *(const float4*)(resid +
                ((size_t)b * Cout + o0 + 4 * ty + c) * Lout + t0 + 4 * tx);
            acc[c][0] += rv.x; acc[c][1] += rv.y; acc[c][2] += rv.z; acc[c][3] += rv.w;
        }
    }
    if (RELU_OUT) {
        #pragma unroll
        for (int c = 0; c < 4; ++c)
            #pragma unroll
            for (int u = 0; u < 4; ++u) acc[c][u] = fmaxf(acc[c][u], 0.f);
    }
    if (TSTORE) {
        // z[(b*L + t)*Cout + d], d = o0+4ty..+3
        #pragma unroll
        for (int u = 0; u < 4; ++u) {
            float4 v; v.x = acc[0][u]; v.y = acc[1][u]; v.z = acc[2][u]; v.w = acc[3][u];
            *(float4*)(out + ((size_t)b * Lout + t0 + 4 * tx + u) * Cout + o0 + 4 * ty) = v;
        }
    } else if (VSTORE) {
        #pragma unroll
        for (int c = 0; c < 4; ++c) {
            float4 v; v.x = acc[c][0]; v.y = acc[c][1]; v.z = acc[c][2]; v.w = acc[c][3];
            *(float4*)(out + ((size_t)b * Cout + o0 + 4 * ty + c) * Lout + t0 + 4 * tx) = v;
        }
    } else {
        #pragma unroll
        for (int c = 0; c < 4; ++c)
            #pragma unroll
            for (int u = 0; u < 4; ++u)
                out[((size_t)b * Cout + o0 + 4 * ty + c) * Lout + t0 + 4 * tx + u] = acc[c][u];
    }
}

// ---------------------------------------------------------------------------
// LDS-tiled ConvTranspose1d stride-2 (parity-split). Block = 64 t2 x 64 co
// for one b. Threads 256 = 16tx(t2) x 16ty(co); thread owns 4 t2 x 4 co ->
// 8 consecutive outputs x 4 co (32 accumulators, even/odd split).
// Per 16-ci chunk: stage input span + weights [ci][k][co64] in LDS.
//   K=3 (pad_lo=1): even(t')=w1*x[t'];            odd(t')=w0*x[t']+w2*x[t'+1]
//   K=5 (pad_lo=2): even(t')=w0*x[t'-1]+w2*x[t']+w4*x[t'+1]; odd(t')=w1*x[t']+w3*x[t'+1]
// Fused ReLU; stores two float4 per co ({E0,O0,E1,O1},{E2,O2,E3,O3}).
// ---------------------------------------------------------------------------
template<int K>
__global__ __launch_bounds__(256) void convttile_k(
    const float* __restrict__ in, const float* __restrict__ w,
    const float* __restrict__ bias, float* __restrict__ out,
    int Cin, int Lin, int Cout)
{
    constexpr int CI    = 16;
    constexpr int SPAN  = (K == 5) ? 66 : 65;   // t2 span incl. halo
    constexpr int SPANP = 68;
    constexpr int WNl   = (K == 5) ? 6 : 5;     // per-thread window

    __shared__ float lin[CI * SPANP];
    __shared__ float lw[CI * K * 64];

    const int tid = threadIdx.x;
    const int tx = tid & 15, ty = tid >> 4;
    const int t20 = blockIdx.x * 64;
    const int o0  = blockIdx.y * 64;
    const int b   = blockIdx.z;
    const int Lout = 2 * Lin;

    float accE[4][4], accO[4][4];
    #pragma unroll
    for (int c = 0; c < 4; ++c) {
        float bv = bias[o0 + 4 * ty + c];
        #pragma unroll
        for (int u = 0; u < 4; ++u) { accE[c][u] = bv; accO[c][u] = bv; }
    }

    const float* inb = in + (size_t)b * Cin * Lin;
    const int p0 = (K == 5) ? (t20 - 1) : t20;

    for (int ci0 = 0; ci0 < Cin; ci0 += CI) {
        __syncthreads();
        // ---- stage input span (zero-fill halo OOB) ----
        for (int idx = tid; idx < CI * SPAN; idx += 256) {
            int ci = idx / SPAN, j = idx - ci * SPAN;
            int p = p0 + j;
            bool ok = (p >= 0) && (p < Lin);
            lin[ci * SPANP + j] = ok ? inb[(size_t)(ci0 + ci) * Lin + p] : 0.0f;
        }
        // ---- stage weights -> [ci][k][co64] ----
        for (int idx = tid; idx < CI * K * 64; idx += 256) {
            int co = idx & 63;
            int r  = idx >> 6;
            int k  = r % K, ci = r / K;
            lw[idx] = w[(size_t)(o0 + co) * Cin * K + (size_t)(ci0 + ci) * K + k];
        }
        __syncthreads();

        for (int ci = 0; ci < CI; ++ci) {
            float win[WNl];
            const float* lrow = &lin[ci * SPANP + 4 * tx];
            #pragma unroll
            for (int j = 0; j < WNl; ++j) win[j] = lrow[j];
            float wc[K][4];
            #pragma unroll
            for (int k = 0; k < K; ++k) {
                const float4 t = *(const float4*)&lw[(ci * K + k) * 64 + 4 * ty];
                wc[k][0] = t.x; wc[k][1] = t.y; wc[k][2] = t.z; wc[k][3] = t.w;
            }
            #pragma unroll
            for (int u = 0; u < 4; ++u) {
                if constexpr (K == 5) {
                    // win[0] = x[t2-1]: even uses {u,u+1,u+2}, odd uses {u+1,u+2}
                    float x0 = win[u], x1 = win[u + 1], x2 = win[u + 2];
                    #pragma unroll
                    for (int c = 0; c < 4; ++c) {
                        accE[c][u] += wc[0][c] * x0 + wc[2][c] * x1 + wc[4][c] * x2;
                        accO[c][u] += wc[1][c] * x1 + wc[3][c] * x2;
                    }
                } else {
                    // win[0] = x[t2]: even uses {u}, odd uses {u,u+1}
                    float x0 = win[u], x1 = win[u + 1];
                    #pragma unroll
                    for (int c = 0; c < 4; ++c) {
                        accE[c][u] += wc[1][c] * x0;
                        accO[c][u] += wc[0][c] * x0 + wc[2][c] * x1;
                    }
                }
            }
        }
    }

    // ---- epilogue: ReLU + interleaved even/odd float4 stores ----
    size_t base = ((size_t)b * Cout + o0 + 4 * ty) * (size_t)Lout + (size_t)(2 * (t20 + 4 * tx));
    #pragma unroll
    for (int c = 0; c < 4; ++c) {
        float4 v0, v1;
        v0.x = fmaxf(accE[c][0], 0.f); v0.y = fmaxf(accO[c][0], 0.f);
        v0.z = fmaxf(accE[c][1], 0.f); v0.w = fmaxf(accO[c][1], 0.f);
        v1.x = fmaxf(accE[c][2], 0.f); v1.y = fmaxf(accO[c][2], 0.f);
        v1.z = fmaxf(accE[c][3], 0.f); v1.w = fmaxf(accO[c][3], 0.f);
        *(float4*)(out + base + (size_t)c * Lout)     = v0;
        *(float4*)(out + base + (size_t)c * Lout + 4) = v1;
    }
}

// ---------------------------------------------------------------------------
// GroupNorm stats -> per-(b,c) scale/shift (eps 1e-5)
// ---------------------------------------------------------------------------
__global__ __launch_bounds__(256) void gnstats_k(
    const float* __restrict__ x, const float* __restrict__ g,
    const float* __restrict__ be, float* __restrict__ scale,
    float* __restrict__ shift, int C, int L, int G)
{
    int tid = threadIdx.x;
    int b = blockIdx.x / G, gr = blockIdx.x % G;
    int cpg = C / G;
    size_t n = (size_t)cpg * L;
    const float* base = x + ((size_t)b * C + (size_t)gr * cpg) * L;
    float s = 0.f, s2 = 0.f;
    for (size_t idx = tid; idx < n; idx += 256) { float v = base[idx]; s += v; s2 += v * v; }
    __shared__ float rs[256], rq[256];
    rs[tid] = s; rq[tid] = s2; __syncthreads();
    for (int off = 128; off > 0; off >>= 1) {
        if (tid < off) { rs[tid] += rs[tid + off]; rq[tid] += rq[tid + off]; }
        __syncthreads();
    }
    float mean = rs[0] / (float)n;
    float var  = rq[0] / (float)n - mean * mean;
    float inv  = rsqrtf(var + 1e-5f);
    if (tid < cpg) {
        int c = gr * cpg + tid;
        float ga = g[c], bb = be[c];
        scale[b * C + c] = inv * ga;
        shift[b * C + c] = bb - mean * inv * ga;
    }
}

// ---------------------------------------------------------------------------
// VQ: 64 positions/block, 16 code-tiles of 64, 4x4 register dot tiles.
// ---------------------------------------------------------------------------
__global__ __launch_bounds__(256) void vq_k(
    const float* __restrict__ z,       // [32768,128]
    const float* __restrict__ cb,      // [1024,128]
    float* __restrict__ out_q,         // [B,128,1024]
    float* __restrict__ lossAcc,
    unsigned int* __restrict__ hist,
    int* __restrict__ ip_out)
{
    const int tid = threadIdx.x;
    const int pbase = blockIdx.x * 64;
    __shared__ float zs[64 * 129];
    __shared__ float cbs[64 * 129];
    __shared__ float cn[64];
    __shared__ float rd[256];
    __shared__ int   ri[256];
    __shared__ int   ip[64];

    for (int f = tid; f < 64 * 128; f += 256) {
        int p = f >> 7, d = f & 127;
        zs[p * 129 + d] = z[(size_t)pbase * 128 + f];
    }

    float mind[4]; int minc[4];
    #pragma unroll
    for (int a = 0; a < 4; ++a) { mind[a] = 3.4e38f; minc[a] = 0; }
    const int tp = tid >> 4, tr = tid & 15;
    const int prow = tp * 4, crow = tr * 4;

    for (int ct = 0; ct < 16; ++ct) {
        __syncthreads();
        for (int f = tid; f < 64 * 128; f += 256) {
            int c = f >> 7, d = f & 127;
            cbs[c * 129 + d] = cb[((size_t)ct * 64 + c) * 128 + d];
        }
        __syncthreads();
        if (tid < 64) {
            float s = 0.f;
            for (int d = 0; d < 128; ++d) { float v = cbs[tid * 129 + d]; s += v * v; }
            cn[tid] = s;
        }
        __syncthreads();
        float dot[4][4];
        #pragma unroll
        for (int a = 0; a < 4; ++a)
            #pragma unroll
            for (int e = 0; e < 4; ++e) dot[a][e] = 0.f;
        for (int d = 0; d < 128; ++d) {
            float za[4], cc[4];
            #pragma unroll
            for (int a = 0; a < 4; ++a) za[a] = zs[(prow + a) * 129 + d];
            #pragma unroll
            for (int e = 0; e < 4; ++e) cc[e] = cbs[(crow + e) * 129 + d];
            #pragma unroll
            for (int a = 0; a < 4; ++a)
                #pragma unroll
                for (int e = 0; e < 4; ++e) dot[a][e] += za[a] * cc[e];
        }
        #pragma unroll
        for (int e = 0; e < 4; ++e) {
            int c = ct * 64 + crow + e;
            float cne = cn[crow + e];
            #pragma unroll
            for (int a = 0; a < 4; ++a) {
                float dist = cne - 2.0f * dot[a][e];
                if (dist < mind[a]) { mind[a] = dist; minc[a] = c; }
            }
        }
    }

    for (int a = 0; a < 4; ++a) {
        __syncthreads();
        rd[tid] = mind[a]; ri[tid] = minc[a];
        __syncthreads();
        if (tr == 0) {
            float bd = rd[tid]; int bi = ri[tid];
            for (int u = 1; u < 16; ++u) {
                float dv = rd[tid + u]; int iv = ri[tid + u];
                if (dv < bd || (dv == bd && iv < bi)) { bd = dv; bi = iv; }
            }
            ip[prow + a] = bi;
            atomicAdd(&hist[bi], 1u);
        }
    }
    __syncthreads();

    if (tid < 64) ip_out[pbase + tid] = ip[tid];

    float lp = 0.f;
    for (int f = tid; f < 64 * 128; f += 256) {
        int p = f >> 7, d = f & 127;
        int gp = pbase + p, b = gp >> 10, l = gp & 1023;
        float qv = cb[(size_t)ip[p] * 128 + d];
        float zv = zs[p * 129 + d];
        float df = qv - zv; lp += df * df;
        out_q[(((size_t)b * 128 + d) << 10) + l] = qv;
    }
    rd[tid] = lp; __syncthreads();
    for (int off = 128; off > 0; off >>= 1) {
        if (tid < off) rd[tid] += rd[tid + off];
        __syncthreads();
    }
    if (tid == 0) atomicAdd(lossAcc, rd[0]);
}

// one-hot enc write (fp32) from indices; enc region was scratch until now.
__global__ __launch_bounds__(256) void enc_k(
    const int* __restrict__ ip, float2* __restrict__ enc)
{
    size_t idx = (size_t)blockIdx.x * 256 + threadIdx.x;   // 16,777,216 float2
    int p  = (int)(idx >> 9);
    int q2 = (int)(idx & 511);
    int best = ip[p];
    int c0 = q2 * 2;
    float2 v;
    v.x = (c0     == best) ? 1.0f : 0.0f;
    v.y = (c0 + 1 == best) ? 1.0f : 0.0f;
    enc[idx] = v;
}

// mean over L=1024 of fp32 [B,D,L]; one block per (b,d)
__global__ __launch_bounds__(256) void pool_k(const float* __restrict__ q, float* __restrict__ zp)
{
    int tid = threadIdx.x;
    const float* row = q + (size_t)blockIdx.x * 1024;
    float s = 0.f;
    for (int l = tid; l < 1024; l += 256) s += row[l];
    __shared__ float rs[256];
    rs[tid] = s; __syncthreads();
    for (int off = 128; off > 0; off >>= 1) {
        if (tid < off) rs[tid] += rs[tid + off];
        __syncthreads();
    }
    if (tid == 0) zp[blockIdx.x] = rs[0] * (1.0f / 1024.0f);
}

// behavior MLP head, single block
__global__ __launch_bounds__(256) void beh_k(
    const float* __restrict__ zp,
    const float* __restrict__ w1, const float* __restrict__ b1,
    const float* __restrict__ w2, const float* __restrict__ b2,
    const float* __restrict__ w3, const float* __restrict__ b3,
    float* __restrict__ out)
{
    __shared__ float zs[32 * 128];
    __shared__ float h1s[32 * 128];
    __shared__ float h2s[32 * 64];
    int tid = threadIdx.x;
    for (int f = tid; f < 4096; f += 256) zs[f] = zp[f];
    __syncthreads();
    for (int f = tid; f < 4096; f += 256) {
        int bi = f >> 7, j = f & 127;
        float acc = b1[j];
        for (int d = 0; d < 128; ++d) acc += zs[bi * 128 + d] * w1[j * 128 + d];
        h1s[f] = fmaxf(acc, 0.f);
    }
    __syncthreads();
    for (int f = tid; f < 2048; f += 256) {
        int bi = f >> 6, j = f & 63;
        float acc = b2[j];
        for (int d = 0; d < 128; ++d) acc += h1s[bi * 128 + d] * w2[j * 128 + d];
        h2s[f] = fmaxf(acc, 0.f);
    }
    __syncthreads();
    if (tid < 128) {
        int bi = tid >> 2, j = tid & 3;
        float acc = b3[j];
        for (int d = 0; d < 64; ++d) acc += h2s[bi * 64 + d] * w3[j * 64 + d];
        out[tid] = acc;
    }
}

__global__ __launch_bounds__(1024) void init_k(unsigned int* hist, float* lossAcc)
{
    hist[threadIdx.x] = 0u;
    if (threadIdx.x == 0) *lossAcc = 0.f;
}

__global__ __launch_bounds__(1024) void fin_k(
    const unsigned int* __restrict__ hist, const float* __restrict__ lossAcc,
    float* __restrict__ out_loss, float* __restrict__ out_perp)
{
    __shared__ float rs[1024];
    int tid = threadIdx.x;
    float avg = (float)hist[tid] * (1.0f / 32768.0f);
    rs[tid] = avg * logf(avg + 1e-10f);
    __syncthreads();
    for (int off = 512; off > 0; off >>= 1) {
        if (tid < off) rs[tid] += rs[tid + off];
        __syncthreads();
    }
    if (tid == 0) {
        out_perp[0] = expf(-rs[0]);
        out_loss[0] = 0.25f * lossAcc[0] * (1.0f / 4194304.0f);
    }
}

// ---------------------------------------------------------------------------
extern "C" void kernel_launch(void* const* d_in, const int* in_sizes, int n_in,
                              void* d_out, int out_size, void* d_ws, size_t ws_size,
                              hipStream_t stream)
{
    const float* X    = (const float*)d_in[0];
    const float* e1w  = (const float*)d_in[1];  const float* e1b = (const float*)d_in[2];
    const float* e2w  = (const float*)d_in[3];  const float* e2b = (const float*)d_in[4];
    const float* e3w  = (const float*)d_in[5];  const float* e3b = (const float*)d_in[6];
    const float* r0g1g = (const float*)d_in[7];  const float* r0g1b = (const float*)d_in[8];
    const float* r0c1w = (const float*)d_in[9];
    const float* r0g2g = (const float*)d_in[10]; const float* r0g2b = (const float*)d_in[11];
    const float* r0c2w = (const float*)d_in[12];
    const float* r1g1g = (const float*)d_in[13]; const float* r1g1b = (const float*)d_in[14];
    const float* r1c1w = (const float*)d_in[15];
    const float* r1g2g = (const float*)d_in[16]; const float* r1g2b = (const float*)d_in[17];
    const float* r1c2w = (const float*)d_in[18];
    const float* pvw  = (const float*)d_in[19]; const float* pvb = (const float*)d_in[20];
    const float* CB   = (const float*)d_in[21];
    const float* d1w  = (const float*)d_in[22]; const float* d1b = (const float*)d_in[23];
    const float* d2w  = (const float*)d_in[24]; const float* d2b = (const float*)d_in[25];
    const float* d3w  = (const float*)d_in[26]; const float* d3b = (const float*)d_in[27];
    const float* bh1w = (const float*)d_in[28]; const float* bh1b = (const float*)d_in[29];
    const float* bh2w = (const float*)d_in[30]; const float* bh2b = (const float*)d_in[31];
    const float* bh3w = (const float*)d_in[32]; const float* bh3b = (const float*)d_in[33];

    // ---- output regions (fp32 elements) ----
    float* out = (float*)d_out;
    const size_t N_XREC = 16777216ull, N_Q = 4194304ull, N_ENC = 33554432ull;
    float* out_loss = out;
    float* out_xrec = out + 1;                          // 64 MiB region
    float* out_perp = out + 1 + N_XREC;
    float* out_q    = out + 2 + N_XREC;                 // 16 MiB region
    float* out_enc  = out + 2 + N_XREC + N_Q;           // 128 MiB region
    float* out_beh  = out + 2 + N_XREC + N_Q + N_ENC;

    // ---- scratch staging (serial lifetimes; FULL-B encoder, HALF-B decoder) ----
    // xrec region: h1 (e1 out, 32x128x4096 = 16,777,216 fl) at out+4 (16B-aligned).
    //   Overruns region by 3 floats into {out_perp, out_q[0..1]} - all rewritten
    //   later by vq_k / fin_k. h3 (32x512x1024, same size) aliases h1 (e3 reads
    //   only h2). c2 writes h3 in-place over its own resid read (elementwise).
    float* h1 = out + 4;
    float* h3 = h1;
    // enc region (33,554,432 fl), base A = out_enc+2 (16B-aligned):
    //   encoder phase: h2 [0,16.8M) ; t2q [16.8M,21.0M) ; z [21.0M,25.2M)
    //   decoder phase: d1o [0,16.8M) ; d2o [16.8M,33.6M) (+2 fl into out_beh,
    //   which beh_k writes afterwards). enc_k finally overwrites whole region.
    float* A   = out_enc + 2;
    float* h2  = A;
    float* t2q = A + 16777216;
    float* z   = A + 20971520;
    float* d1o = A;
    float* d2o = A + 16777216;

    // ---- d_ws: smalls ONLY (~320 KB) ----
    float* W = (float*)d_ws;
    float* lossA = W;                              // 1 (+pad 16)
    unsigned int* hist = (unsigned int*)(W + 16);  // 1,024
    float* zp   = W + 16 + 1024;                   // 4,096
    int* ipArr  = (int*)(W + 16 + 1024 + 4096);    // 32,768
    float* scA  = W + 16 + 1024 + 4096 + 32768;    // 16,384 (32 b x 512)
    float* shA  = scA + 16384;                     // 16,384
    float* scB  = shA + 16384;                     // 4,096 (32 b x 128)
    float* shB  = scB + 4096;                      // 4,096

    init_k<<<dim3(1), dim3(1024), 0, stream>>>(hist, lossA);

    // ---- encoder (full batch B=32) ----
    // e1: K7 s1 p3, 128->128, L4096
    convtile_k<7,1,false,false,true,false,true><<<dim3(64, 2, 32), 256, 0, stream>>>(
        X, e1w, e1b, h1, nullptr, nullptr, nullptr, 128, 4096, 4096, 3, 128);
    // e2: K5 s2 p2, 128->256, L4096->2048
    convtile_k<5,2,false,false,true,false,true><<<dim3(32, 4, 32), 256, 0, stream>>>(
        h1, e2w, e2b, h2, nullptr, nullptr, nullptr, 128, 4096, 2048, 2, 256);
    // e3: K3 s2 p1, 256->512, 2048->1024 (writes h3, aliasing h1; reads only h2)
    convtile_k<3,2,false,false,false,false,true><<<dim3(16, 8, 32), 256, 0, stream>>>(
        h2, e3w, e3b, h3, nullptr, nullptr, nullptr, 256, 2048, 1024, 1, 512);

    // res block 0
    gnstats_k<<<dim3(256), 256, 0, stream>>>(h3, r0g1g, r0g1b, scA, shA, 512, 1024, 8);
    convtile_k<3,1,true,false,false,false,true><<<dim3(16, 2, 32), 256, 0, stream>>>(
        h3, r0c1w, nullptr, t2q, scA, shA, nullptr, 512, 1024, 1024, 1, 128);
    gnstats_k<<<dim3(256), 256, 0, stream>>>(t2q, r0g2g, r0g2b, scB, shB, 128, 1024, 8);
    convtile_k<1,1,true,true,false,false,true><<<dim3(16, 8, 32), 256, 0, stream>>>(
        t2q, r0c2w, nullptr, h3, scB, shB, h3, 128, 1024, 1024, 0, 512);

    // res block 1
    gnstats_k<<<dim3(256), 256, 0, stream>>>(h3, r1g1g, r1g1b, scA, shA, 512, 1024, 8);
    convtile_k<3,1,true,false,false,false,true><<<dim3(16, 2, 32), 256, 0, stream>>>(
        h3, r1c1w, nullptr, t2q, scA, shA, nullptr, 512, 1024, 1024, 1, 128);
    gnstats_k<<<dim3(256), 256, 0, stream>>>(t2q, r1g2g, r1g2b, scB, shB, 128, 1024, 8);
    convtile_k<1,1,true,true,false,false,true><<<dim3(16, 8, 32), 256, 0, stream>>>(
        t2q, r1c2w, nullptr, h3, scB, shB, h3, 128, 1024, 1024, 0, 512);

    // pre-VQ 1x1 conv 512->128, transposed store -> z [pos,128]
    convtile_k<1,1,false,false,false,true,true><<<dim3(16, 2, 32), 256, 0, stream>>>(
        h3, pvw, pvb, z, nullptr, nullptr, nullptr, 512, 1024, 1024, 0, 128);

    // ---- VQ: writes out_q (final fp32), hist, loss, indices ----
    vq_k<<<dim3(512), 256, 0, stream>>>(z, CB, out_q, lossA, hist, ipArr);

    // ---- decoder, per batch-HALF (16 samples); LDS-tiled transpose convs ----
    for (int h = 0; h < 2; ++h) {
        convttile_k<3><<<dim3(16, 8, 16), 256, 0, stream>>>(
            out_q + (size_t)h * 2097152, d1w, d1b, d1o, 128, 1024, 512);
        convttile_k<5><<<dim3(32, 4, 16), 256, 0, stream>>>(
            d1o, d2w, d2b, d2o, 512, 2048, 256);
        convtile_k<7,1,false,false,false,false,false><<<dim3(64, 2, 16), 256, 0, stream>>>(
            d2o, d3w, d3b, out_xrec + (size_t)h * 8388608, nullptr, nullptr, nullptr,
            256, 4096, 4096, 3, 128);
    }

    // ---- behavior head (after decoder: d2o overhangs 2 floats into out_beh) ----
    pool_k<<<dim3(4096), 256, 0, stream>>>(out_q, zp);
    beh_k<<<dim3(1), 256, 0, stream>>>(zp, bh1w, bh1b, bh2w, bh2b, bh3w, bh3b, out_beh);

    // ---- one-hot enc (overwrites enc-region scratch with the real output) ----
    enc_k<<<dim3(65536), 256, 0, stream>>>(ipArr, (float2*)out_enc);

    // ---- loss + perplexity ----
    fin_k<<<dim3(1), 1024, 0, stream>>>(hist, lossA, out_loss, out_perp);
}

// Round 6
// 6068.927 us; speedup vs baseline: 2.1953x; 2.1953x over previous
//
#include <hip/hip_runtime.h>

// All tensors fp32 (per the reference: inputs, weights, outputs all float32).

// ---------------------------------------------------------------------------
// LDS-tiled direct conv1d ("implicit GEMM"). Block = 64 co x 64 t for one b.
// Threads 256 = 16tx(t) x 16ty(co); each thread 4co x 4t register tile.
// Per ci-chunk (CI channels): stage input span (GN+ReLU fused here) and
// weights [ci][k][64co] in LDS, then FMA from aligned LDS vectors.
//   TSTORE: write transposed [pos][co] layout (pre-VQ z).
//   VSTORE: float4 stores (dst 16B-aligned); else scalar stores.
// ---------------------------------------------------------------------------
template<int K, int S, bool GN, bool RESID, bool RELU_OUT, bool TSTORE, bool VSTORE>
__global__ __launch_bounds__(256) void convtile_k(
    const float* __restrict__ in, const float* __restrict__ w,
    const float* __restrict__ bias, float* __restrict__ out,
    const float* __restrict__ scale, const float* __restrict__ shift,
    const float* __restrict__ resid,
    int Cin, int Lin, int Lout, int pad, int Cout)
{
    constexpr int CI    = (K == 1) ? 32 : 16;   // ci chunk
    constexpr int SPAN  = 63 * S + K;           // staged input span per ci
    constexpr int SPANP = (SPAN + 3) & ~3;      // 16B-aligned row stride
    constexpr int WN    = 3 * S + K;            // per-thread window

    __shared__ float lin[CI * SPANP];
    __shared__ float lw[CI * K * 64];

    const int tid = threadIdx.x;
    const int tx = tid & 15, ty = tid >> 4;
    const int t0 = blockIdx.x * 64;
    const int o0 = blockIdx.y * 64;
    const int b  = blockIdx.z;

    float acc[4][4];
    #pragma unroll
    for (int c = 0; c < 4; ++c) {
        float bv = bias ? bias[o0 + 4 * ty + c] : 0.0f;
        #pragma unroll
        for (int u = 0; u < 4; ++u) acc[c][u] = bv;
    }

    const float* inb = in + (size_t)b * Cin * Lin;
    const int p0 = t0 * S - pad;

    for (int ci0 = 0; ci0 < Cin; ci0 += CI) {
        __syncthreads();
        // ---- stage input (coalesced; GN+ReLU fused; zero-fill OOB) ----
        for (int idx = tid; idx < CI * SPAN; idx += 256) {
            int ci = idx / SPAN, j = idx - ci * SPAN;
            int p = p0 + j;
            bool ok = (p >= 0) && (p < Lin);
            float v = ok ? inb[(size_t)(ci0 + ci) * Lin + p] : 0.0f;
            if (GN) {
                float sc = scale[b * Cin + ci0 + ci];
                float sh = shift[b * Cin + ci0 + ci];
                v = ok ? fmaxf(v * sc + sh, 0.0f) : 0.0f;
            }
            lin[ci * SPANP + j] = v;
        }
        // ---- stage weights -> [ci][k][co64] (LDS writes conflict-free) ----
        for (int idx = tid; idx < CI * K * 64; idx += 256) {
            int co = idx & 63;
            int r  = idx >> 6;
            int k  = r % K, ci = r / K;
            lw[idx] = w[(size_t)(o0 + co) * Cin * K + (size_t)(ci0 + ci) * K + k];
        }
        __syncthreads();

        for (int ci = 0; ci < CI; ++ci) {
            float win[WN];
            const float* lrow = &lin[ci * SPANP + 4 * S * tx];
            #pragma unroll
            for (int j = 0; j < WN; ++j) win[j] = lrow[j];
            #pragma unroll
            for (int k = 0; k < K; ++k) {
                const float4 wv = *(const float4*)&lw[(ci * K + k) * 64 + 4 * ty];
                #pragma unroll
                for (int u = 0; u < 4; ++u) {
                    float x = win[u * S + k];
                    acc[0][u] += x * wv.x;
                    acc[1][u] += x * wv.y;
                    acc[2][u] += x * wv.z;
                    acc[3][u] += x * wv.w;
                }
            }
        }
    }

    // ---- epilogue ----
    if (RESID) {
        #pragma unroll
        for (int c = 0; c < 4; ++c) {
            const float4 rv = *(const float4*)(resid +
                ((size_t)b * Cout + o0 + 4 * ty + c) * Lout + t0 + 4 * tx);
            acc[c][0] += rv.x; acc[c][1] += rv.y; acc[c][2] += rv.z; acc[c][3] += rv.w;
        }
    }
    if (RELU_OUT) {
        #pragma unroll
        for (int c = 0; c < 4; ++c)
            #pragma unroll
            for (int u = 0; u < 4; ++u) acc[c][u] = fmaxf(acc[c][u], 0.f);
    }
    if (TSTORE) {
        // z[(b*L + t)*Cout + d], d = o0+4ty..+3
        #pragma unroll
        for (int u = 0; u < 4; ++u) {
            float4 v; v.x = acc[0][u]; v.y = acc[1][u]; v.z = acc[2][u]; v.w = acc[3][u];
            *(float4*)(out + ((size_t)b * Lout + t0 + 4 * tx + u) * Cout + o0 + 4 * ty) = v;
        }
    } else if (VSTORE) {
        #pragma unroll
        for (int c = 0; c < 4; ++c) {
            float4 v; v.x = acc[c][0]; v.y = acc[c][1]; v.z = acc[c][2]; v.w = acc[c][3];
            *(float4*)(out + ((size_t)b * Cout + o0 + 4 * ty + c) * Lout + t0 + 4 * tx) = v;
        }
    } else {
        #pragma unroll
        for (int c = 0; c < 4; ++c)
            #pragma unroll
            for (int u = 0; u < 4; ++u)
                out[((size_t)b * Cout + o0 + 4 * ty + c) * Lout + t0 + 4 * tx + u] = acc[c][u];
    }
}

// ---------------------------------------------------------------------------
// LDS-tiled ConvTranspose1d stride-2 (parity-split). Block = 64 t2 x 64 co
// for one b. Threads 256 = 16tx(t2) x 16ty(co); thread owns 4 t2 x 4 co ->
// 8 consecutive outputs x 4 co (32 accumulators, even/odd split).
// Inner loop mirrors convtile_k: per k-tap, ONE float4 weight load consumed
// immediately by 16 FMAs (short live ranges -> low VGPR; round-5's wc[K][4]
// register staging gave VGPR=172 / 12% occupancy / 2x regression).
//   K=3 (pad_lo=1): even(t')=w1*x[t'];            odd(t')=w0*x[t']+w2*x[t'+1]
//   K=5 (pad_lo=2): even(t')=w0*x[t'-1]+w2*x[t']+w4*x[t'+1]; odd(t')=w1*x[t']+w3*x[t'+1]
// Per-tap mapping (window offset joff, parity target):
//   K=5: k=0->E win[u]; k=1->O win[u+1]; k=2->E win[u+1]; k=3->O win[u+2]; k=4->E win[u+2]
//   K=3: k=0->O win[u]; k=1->E win[u];   k=2->O win[u+1]
// Fused ReLU; stores two float4 per co ({E0,O0,E1,O1},{E2,O2,E3,O3}).
// ---------------------------------------------------------------------------
template<int K>
__global__ __launch_bounds__(256, 4) void convttile_k(
    const float* __restrict__ in, const float* __restrict__ w,
    const float* __restrict__ bias, float* __restrict__ out,
    int Cin, int Lin, int Cout)
{
    constexpr int CI    = 16;
    constexpr int SPAN  = (K == 5) ? 66 : 65;   // t2 span incl. halo
    constexpr int SPANP = 68;
    constexpr int WNl   = (K == 5) ? 6 : 5;     // per-thread window

    __shared__ float lin[CI * SPANP];
    __shared__ float lw[CI * K * 64];

    const int tid = threadIdx.x;
    const int tx = tid & 15, ty = tid >> 4;
    const int t20 = blockIdx.x * 64;
    const int o0  = blockIdx.y * 64;
    const int b   = blockIdx.z;
    const int Lout = 2 * Lin;

    float accE[4][4], accO[4][4];
    #pragma unroll
    for (int c = 0; c < 4; ++c) {
        float bv = bias[o0 + 4 * ty + c];
        #pragma unroll
        for (int u = 0; u < 4; ++u) { accE[c][u] = bv; accO[c][u] = bv; }
    }

    const float* inb = in + (size_t)b * Cin * Lin;
    const int p0 = (K == 5) ? (t20 - 1) : t20;

    for (int ci0 = 0; ci0 < Cin; ci0 += CI) {
        __syncthreads();
        // ---- stage input span (zero-fill halo OOB) ----
        for (int idx = tid; idx < CI * SPAN; idx += 256) {
            int ci = idx / SPAN, j = idx - ci * SPAN;
            int p = p0 + j;
            bool ok = (p >= 0) && (p < Lin);
            lin[ci * SPANP + j] = ok ? inb[(size_t)(ci0 + ci) * Lin + p] : 0.0f;
        }
        // ---- stage weights -> [ci][k][co64] ----
        for (int idx = tid; idx < CI * K * 64; idx += 256) {
            int co = idx & 63;
            int r  = idx >> 6;
            int k  = r % K, ci = r / K;
            lw[idx] = w[(size_t)(o0 + co) * Cin * K + (size_t)(ci0 + ci) * K + k];
        }
        __syncthreads();

        for (int ci = 0; ci < CI; ++ci) {
            float win[WNl];
            const float* lrow = &lin[ci * SPANP + 4 * tx];
            #pragma unroll
            for (int j = 0; j < WNl; ++j) win[j] = lrow[j];
            #pragma unroll
            for (int k = 0; k < K; ++k) {
                const float4 wv = *(const float4*)&lw[(ci * K + k) * 64 + 4 * ty];
                const int  joff = (K == 5) ? ((k + 1) >> 1) : (k >> 1);
                const bool toE  = (K == 5) ? ((k & 1) == 0) : (k == 1);
                #pragma unroll
                for (int u = 0; u < 4; ++u) {
                    float x = win[u + joff];
                    if (toE) {
                        accE[0][u] += x * wv.x;
                        accE[1][u] += x * wv.y;
                        accE[2][u] += x * wv.z;
                        accE[3][u] += x * wv.w;
                    } else {
                        accO[0][u] += x * wv.x;
                        accO[1][u] += x * wv.y;
                        accO[2][u] += x * wv.z;
                        accO[3][u] += x * wv.w;
                    }
                }
            }
        }
    }

    // ---- epilogue: ReLU + interleaved even/odd float4 stores ----
    size_t base = ((size_t)b * Cout + o0 + 4 * ty) * (size_t)Lout + (size_t)(2 * (t20 + 4 * tx));
    #pragma unroll
    for (int c = 0; c < 4; ++c) {
        float4 v0, v1;
        v0.x = fmaxf(accE[c][0], 0.f); v0.y = fmaxf(accO[c][0], 0.f);
        v0.z = fmaxf(accE[c][1], 0.f); v0.w = fmaxf(accO[c][1], 0.f);
        v1.x = fmaxf(accE[c][2], 0.f); v1.y = fmaxf(accO[c][2], 0.f);
        v1.z = fmaxf(accE[c][3], 0.f); v1.w = fmaxf(accO[c][3], 0.f);
        *(float4*)(out + base + (size_t)c * Lout)     = v0;
        *(float4*)(out + base + (size_t)c * Lout + 4) = v1;
    }
}

// ---------------------------------------------------------------------------
// GroupNorm stats -> per-(b,c) scale/shift (eps 1e-5)
// ---------------------------------------------------------------------------
__global__ __launch_bounds__(256) void gnstats_k(
    const float* __restrict__ x, const float* __restrict__ g,
    const float* __restrict__ be, float* __restrict__ scale,
    float* __restrict__ shift, int C, int L, int G)
{
    int tid = threadIdx.x;
    int b = blockIdx.x / G, gr = blockIdx.x % G;
    int cpg = C / G;
    size_t n = (size_t)cpg * L;
    const float* base = x + ((size_t)b * C + (size_t)gr * cpg) * L;
    float s = 0.f, s2 = 0.f;
    for (size_t idx = tid; idx < n; idx += 256) { float v = base[idx]; s += v; s2 += v * v; }
    __shared__ float rs[256], rq[256];
    rs[tid] = s; rq[tid] = s2; __syncthreads();
    for (int off = 128; off > 0; off >>= 1) {
        if (tid < off) { rs[tid] += rs[tid + off]; rq[tid] += rq[tid + off]; }
        __syncthreads();
    }
    float mean = rs[0] / (float)n;
    float var  = rq[0] / (float)n - mean * mean;
    float inv  = rsqrtf(var + 1e-5f);
    if (tid < cpg) {
        int c = gr * cpg + tid;
        float ga = g[c], bb = be[c];
        scale[b * C + c] = inv * ga;
        shift[b * C + c] = bb - mean * inv * ga;
    }
}

// ---------------------------------------------------------------------------
// VQ: 64 positions/block, 16 code-tiles of 64, 4x4 register dot tiles.
// ---------------------------------------------------------------------------
__global__ __launch_bounds__(256) void vq_k(
    const float* __restrict__ z,       // [32768,128]
    const float* __restrict__ cb,      // [1024,128]
    float* __restrict__ out_q,         // [B,128,1024]
    float* __restrict__ lossAcc,
    unsigned int* __restrict__ hist,
    int* __restrict__ ip_out)
{
    const int tid = threadIdx.x;
    const int pbase = blockIdx.x * 64;
    __shared__ float zs[64 * 129];
    __shared__ float cbs[64 * 129];
    __shared__ float cn[64];
    __shared__ float rd[256];
    __shared__ int   ri[256];
    __shared__ int   ip[64];

    for (int f = tid; f < 64 * 128; f += 256) {
        int p = f >> 7, d = f & 127;
        zs[p * 129 + d] = z[(size_t)pbase * 128 + f];
    }

    float mind[4]; int minc[4];
    #pragma unroll
    for (int a = 0; a < 4; ++a) { mind[a] = 3.4e38f; minc[a] = 0; }
    const int tp = tid >> 4, tr = tid & 15;
    const int prow = tp * 4, crow = tr * 4;

    for (int ct = 0; ct < 16; ++ct) {
        __syncthreads();
        for (int f = tid; f < 64 * 128; f += 256) {
            int c = f >> 7, d = f & 127;
            cbs[c * 129 + d] = cb[((size_t)ct * 64 + c) * 128 + d];
        }
        __syncthreads();
        if (tid < 64) {
            float s = 0.f;
            for (int d = 0; d < 128; ++d) { float v = cbs[tid * 129 + d]; s += v * v; }
            cn[tid] = s;
        }
        __syncthreads();
        float dot[4][4];
        #pragma unroll
        for (int a = 0; a < 4; ++a)
            #pragma unroll
            for (int e = 0; e < 4; ++e) dot[a][e] = 0.f;
        for (int d = 0; d < 128; ++d) {
            float za[4], cc[4];
            #pragma unroll
            for (int a = 0; a < 4; ++a) za[a] = zs[(prow + a) * 129 + d];
            #pragma unroll
            for (int e = 0; e < 4; ++e) cc[e] = cbs[(crow + e) * 129 + d];
            #pragma unroll
            for (int a = 0; a < 4; ++a)
                #pragma unroll
                for (int e = 0; e < 4; ++e) dot[a][e] += za[a] * cc[e];
        }
        #pragma unroll
        for (int e = 0; e < 4; ++e) {
            int c = ct * 64 + crow + e;
            float cne = cn[crow + e];
            #pragma unroll
            for (int a = 0; a < 4; ++a) {
                float dist = cne - 2.0f * dot[a][e];
                if (dist < mind[a]) { mind[a] = dist; minc[a] = c; }
            }
        }
    }

    for (int a = 0; a < 4; ++a) {
        __syncthreads();
        rd[tid] = mind[a]; ri[tid] = minc[a];
        __syncthreads();
        if (tr == 0) {
            float bd = rd[tid]; int bi = ri[tid];
            for (int u = 1; u < 16; ++u) {
                float dv = rd[tid + u]; int iv = ri[tid + u];
                if (dv < bd || (dv == bd && iv < bi)) { bd = dv; bi = iv; }
            }
            ip[prow + a] = bi;
            atomicAdd(&hist[bi], 1u);
        }
    }
    __syncthreads();

    if (tid < 64) ip_out[pbase + tid] = ip[tid];

    float lp = 0.f;
    for (int f = tid; f < 64 * 128; f += 256) {
        int p = f >> 7, d = f & 127;
        int gp = pbase + p, b = gp >> 10, l = gp & 1023;
        float qv = cb[(size_t)ip[p] * 128 + d];
        float zv = zs[p * 129 + d];
        float df = qv - zv; lp += df * df;
        out_q[(((size_t)b * 128 + d) << 10) + l] = qv;
    }
    rd[tid] = lp; __syncthreads();
    for (int off = 128; off > 0; off >>= 1) {
        if (tid < off) rd[tid] += rd[tid + off];
        __syncthreads();
    }
    if (tid == 0) atomicAdd(lossAcc, rd[0]);
}

// one-hot enc write (fp32) from indices; enc region was scratch until now.
__global__ __launch_bounds__(256) void enc_k(
    const int* __restrict__ ip, float2* __restrict__ enc)
{
    size_t idx = (size_t)blockIdx.x * 256 + threadIdx.x;   // 16,777,216 float2
    int p  = (int)(idx >> 9);
    int q2 = (int)(idx & 511);
    int best = ip[p];
    int c0 = q2 * 2;
    float2 v;
    v.x = (c0     == best) ? 1.0f : 0.0f;
    v.y = (c0 + 1 == best) ? 1.0f : 0.0f;
    enc[idx] = v;
}

// mean over L=1024 of fp32 [B,D,L]; one block per (b,d)
__global__ __launch_bounds__(256) void pool_k(const float* __restrict__ q, float* __restrict__ zp)
{
    int tid = threadIdx.x;
    const float* row = q + (size_t)blockIdx.x * 1024;
    float s = 0.f;
    for (int l = tid; l < 1024; l += 256) s += row[l];
    __shared__ float rs[256];
    rs[tid] = s; __syncthreads();
    for (int off = 128; off > 0; off >>= 1) {
        if (tid < off) rs[tid] += rs[tid + off];
        __syncthreads();
    }
    if (tid == 0) zp[blockIdx.x] = rs[0] * (1.0f / 1024.0f);
}

// behavior MLP head, single block
__global__ __launch_bounds__(256) void beh_k(
    const float* __restrict__ zp,
    const float* __restrict__ w1, const float* __restrict__ b1,
    const float* __restrict__ w2, const float* __restrict__ b2,
    const float* __restrict__ w3, const float* __restrict__ b3,
    float* __restrict__ out)
{
    __shared__ float zs[32 * 128];
    __shared__ float h1s[32 * 128];
    __shared__ float h2s[32 * 64];
    int tid = threadIdx.x;
    for (int f = tid; f < 4096; f += 256) zs[f] = zp[f];
    __syncthreads();
    for (int f = tid; f < 4096; f += 256) {
        int bi = f >> 7, j = f & 127;
        float acc = b1[j];
        for (int d = 0; d < 128; ++d) acc += zs[bi * 128 + d] * w1[j * 128 + d];
        h1s[f] = fmaxf(acc, 0.f);
    }
    __syncthreads();
    for (int f = tid; f < 2048; f += 256) {
        int bi = f >> 6, j = f & 63;
        float acc = b2[j];
        for (int d = 0; d < 128; ++d) acc += h1s[bi * 128 + d] * w2[j * 128 + d];
        h2s[f] = fmaxf(acc, 0.f);
    }
    __syncthreads();
    if (tid < 128) {
        int bi = tid >> 2, j = tid & 3;
        float acc = b3[j];
        for (int d = 0; d < 64; ++d) acc += h2s[bi * 64 + d] * w3[j * 64 + d];
        out[tid] = acc;
    }
}

__global__ __launch_bounds__(1024) void init_k(unsigned int* hist, float* lossAcc)
{
    hist[threadIdx.x] = 0u;
    if (threadIdx.x == 0) *lossAcc = 0.f;
}

__global__ __launch_bounds__(1024) void fin_k(
    const unsigned int* __restrict__ hist, const float* __restrict__ lossAcc,
    float* __restrict__ out_loss, float* __restrict__ out_perp)
{
    __shared__ float rs[1024];
    int tid = threadIdx.x;
    float avg = (float)hist[tid] * (1.0f / 32768.0f);
    rs[tid] = avg * logf(avg + 1e-10f);
    __syncthreads();
    for (int off = 512; off > 0; off >>= 1) {
        if (tid < off) rs[tid] += rs[tid + off];
        __syncthreads();
    }
    if (tid == 0) {
        out_perp[0] = expf(-rs[0]);
        out_loss[0] = 0.25f * lossAcc[0] * (1.0f / 4194304.0f);
    }
}

// ---------------------------------------------------------------------------
extern "C" void kernel_launch(void* const* d_in, const int* in_sizes, int n_in,
                              void* d_out, int out_size, void* d_ws, size_t ws_size,
                              hipStream_t stream)
{
    const float* X    = (const float*)d_in[0];
    const float* e1w  = (const float*)d_in[1];  const float* e1b = (const float*)d_in[2];
    const float* e2w  = (const float*)d_in[3];  const float* e2b = (const float*)d_in[4];
    const float* e3w  = (const float*)d_in[5];  const float* e3b = (const float*)d_in[6];
    const float* r0g1g = (const float*)d_in[7];  const float* r0g1b = (const float*)d_in[8];
    const float* r0c1w = (const float*)d_in[9];
    const float* r0g2g = (const float*)d_in[10]; const float* r0g2b = (const float*)d_in[11];
    const float* r0c2w = (const float*)d_in[12];
    const float* r1g1g = (const float*)d_in[13]; const float* r1g1b = (const float*)d_in[14];
    const float* r1c1w = (const float*)d_in[15];
    const float* r1g2g = (const float*)d_in[16]; const float* r1g2b = (const float*)d_in[17];
    const float* r1c2w = (const float*)d_in[18];
    const float* pvw  = (const float*)d_in[19]; const float* pvb = (const float*)d_in[20];
    const float* CB   = (const float*)d_in[21];
    const float* d1w  = (const float*)d_in[22]; const float* d1b = (const float*)d_in[23];
    const float* d2w  = (const float*)d_in[24]; const float* d2b = (const float*)d_in[25];
    const float* d3w  = (const float*)d_in[26]; const float* d3b = (const float*)d_in[27];
    const float* bh1w = (const float*)d_in[28]; const float* bh1b = (const float*)d_in[29];
    const float* bh2w = (const float*)d_in[30]; const float* bh2b = (const float*)d_in[31];
    const float* bh3w = (const float*)d_in[32]; const float* bh3b = (const float*)d_in[33];

    // ---- output regions (fp32 elements) ----
    float* out = (float*)d_out;
    const size_t N_XREC = 16777216ull, N_Q = 4194304ull, N_ENC = 33554432ull;
    float* out_loss = out;
    float* out_xrec = out + 1;                          // 64 MiB region
    float* out_perp = out + 1 + N_XREC;
    float* out_q    = out + 2 + N_XREC;                 // 16 MiB region
    float* out_enc  = out + 2 + N_XREC + N_Q;           // 128 MiB region
    float* out_beh  = out + 2 + N_XREC + N_Q + N_ENC;

    // ---- scratch staging (serial lifetimes; FULL-B encoder, HALF-B decoder) ----
    // xrec region: h1 (e1 out, 32x128x4096 = 16,777,216 fl) at out+4 (16B-aligned).
    //   Overruns region by 3 floats into {out_perp, out_q[0..1]} - all rewritten
    //   later by vq_k / fin_k. h3 (32x512x1024, same size) aliases h1 (e3 reads
    //   only h2). c2 writes h3 in-place over its own resid read (elementwise).
    float* h1 = out + 4;
    float* h3 = h1;
    // enc region (33,554,432 fl), base A = out_enc+2 (16B-aligned):
    //   encoder phase: h2 [0,16.8M) ; t2q [16.8M,21.0M) ; z [21.0M,25.2M)
    //   decoder phase: d1o [0,16.8M) ; d2o [16.8M,33.6M) (+2 fl into out_beh,
    //   which beh_k writes afterwards). enc_k finally overwrites whole region.
    float* A   = out_enc + 2;
    float* h2  = A;
    float* t2q = A + 16777216;
    float* z   = A + 20971520;
    float* d1o = A;
    float* d2o = A + 16777216;

    // ---- d_ws: smalls ONLY (~320 KB) ----
    float* W = (float*)d_ws;
    float* lossA = W;                              // 1 (+pad 16)
    unsigned int* hist = (unsigned int*)(W + 16);  // 1,024
    float* zp   = W + 16 + 1024;                   // 4,096
    int* ipArr  = (int*)(W + 16 + 1024 + 4096);    // 32,768
    float* scA  = W + 16 + 1024 + 4096 + 32768;    // 16,384 (32 b x 512)
    float* shA  = scA + 16384;                     // 16,384
    float* scB  = shA + 16384;                     // 4,096 (32 b x 128)
    float* shB  = scB + 4096;                      // 4,096

    init_k<<<dim3(1), dim3(1024), 0, stream>>>(hist, lossA);

    // ---- encoder (full batch B=32) ----
    // e1: K7 s1 p3, 128->128, L4096
    convtile_k<7,1,false,false,true,false,true><<<dim3(64, 2, 32), 256, 0, stream>>>(
        X, e1w, e1b, h1, nullptr, nullptr, nullptr, 128, 4096, 4096, 3, 128);
    // e2: K5 s2 p2, 128->256, L4096->2048
    convtile_k<5,2,false,false,true,false,true><<<dim3(32, 4, 32), 256, 0, stream>>>(
        h1, e2w, e2b, h2, nullptr, nullptr, nullptr, 128, 4096, 2048, 2, 256);
    // e3: K3 s2 p1, 256->512, 2048->1024 (writes h3, aliasing h1; reads only h2)
    convtile_k<3,2,false,false,false,false,true><<<dim3(16, 8, 32), 256, 0, stream>>>(
        h2, e3w, e3b, h3, nullptr, nullptr, nullptr, 256, 2048, 1024, 1, 512);

    // res block 0
    gnstats_k<<<dim3(256), 256, 0, stream>>>(h3, r0g1g, r0g1b, scA, shA, 512, 1024, 8);
    convtile_k<3,1,true,false,false,false,true><<<dim3(16, 2, 32), 256, 0, stream>>>(
        h3, r0c1w, nullptr, t2q, scA, shA, nullptr, 512, 1024, 1024, 1, 128);
    gnstats_k<<<dim3(256), 256, 0, stream>>>(t2q, r0g2g, r0g2b, scB, shB, 128, 1024, 8);
    convtile_k<1,1,true,true,false,false,true><<<dim3(16, 8, 32), 256, 0, stream>>>(
        t2q, r0c2w, nullptr, h3, scB, shB, h3, 128, 1024, 1024, 0, 512);

    // res block 1
    gnstats_k<<<dim3(256), 256, 0, stream>>>(h3, r1g1g, r1g1b, scA, shA, 512, 1024, 8);
    convtile_k<3,1,true,false,false,false,true><<<dim3(16, 2, 32), 256, 0, stream>>>(
        h3, r1c1w, nullptr, t2q, scA, shA, nullptr, 512, 1024, 1024, 1, 128);
    gnstats_k<<<dim3(256), 256, 0, stream>>>(t2q, r1g2g, r1g2b, scB, shB, 128, 1024, 8);
    convtile_k<1,1,true,true,false,false,true><<<dim3(16, 8, 32), 256, 0, stream>>>(
        t2q, r1c2w, nullptr, h3, scB, shB, h3, 128, 1024, 1024, 0, 512);

    // pre-VQ 1x1 conv 512->128, transposed store -> z [pos,128]
    convtile_k<1,1,false,false,false,true,true><<<dim3(16, 2, 32), 256, 0, stream>>>(
        h3, pvw, pvb, z, nullptr, nullptr, nullptr, 512, 1024, 1024, 0, 128);

    // ---- VQ: writes out_q (final fp32), hist, loss, indices ----
    vq_k<<<dim3(512), 256, 0, stream>>>(z, CB, out_q, lossA, hist, ipArr);

    // ---- decoder, per batch-HALF (16 samples); LDS-tiled transpose convs ----
    for (int h = 0; h < 2; ++h) {
        convttile_k<3><<<dim3(16, 8, 16), 256, 0, stream>>>(
            out_q + (size_t)h * 2097152, d1w, d1b, d1o, 128, 1024, 512);
        convttile_k<5><<<dim3(32, 4, 16), 256, 0, stream>>>(
            d1o, d2w, d2b, d2o, 512, 2048, 256);
        convtile_k<7,1,false,false,false,false,false><<<dim3(64, 2, 16), 256, 0, stream>>>(
            d2o, d3w, d3b, out_xrec + (size_t)h * 8388608, nullptr, nullptr, nullptr,
            256, 4096, 4096, 3, 128);
    }

    // ---- behavior head (after decoder: d2o overhangs 2 floats into out_beh) ----
    pool_k<<<dim3(4096), 256, 0, stream>>>(out_q, zp);
    beh_k<<<dim3(1), 256, 0, stream>>>(zp, bh1w, bh1b, bh2w, bh2b, bh3w, bh3b, out_beh);

    // ---- one-hot enc (overwrites enc-region scratch with the real output) ----
    enc_k<<<dim3(65536), 256, 0, stream>>>(ipArr, (float2*)out_enc);

    // ---- loss + perplexity ----
    fin_k<<<dim3(1), 1024, 0, stream>>>(hist, lossA, out_loss, out_perp);
}

// Round 7
// 4643.020 us; speedup vs baseline: 2.8695x; 1.3071x over previous
//
#include <hip/hip_runtime.h>

// All tensors fp32 (per the reference: inputs, weights, outputs all float32).

// ---------------------------------------------------------------------------
// LDS-tiled direct conv1d ("implicit GEMM"). Block = 64 co x 64 t for one b.
// Threads 256 = 16tx(t) x 16ty(co); each thread 4co x 4t register tile.
// Staging (round 7): input rows cooperatively (1 row / 16-thread group,
// pow2 index math, GN scale hoisted per chunk); weights via 4-threads-per-co
// contiguous float4 loads with compile-time (ci,k) split (no div/mod, was
// 64-way-scattered + div-by-K per element). lw stride 68 keeps the scatter
// writes <=2-way bank-aliased. win loaded as float4s.
//   TSTORE: write transposed [pos][co] layout (pre-VQ z).
//   VSTORE: float4 stores (dst 16B-aligned); else scalar stores.
// ---------------------------------------------------------------------------
template<int K, int S, bool GN, bool RESID, bool RELU_OUT, bool TSTORE, bool VSTORE>
__global__ __launch_bounds__(256) void convtile_k(
    const float* __restrict__ in, const float* __restrict__ w,
    const float* __restrict__ bias, float* __restrict__ out,
    const float* __restrict__ scale, const float* __restrict__ shift,
    const float* __restrict__ resid,
    int Cin, int Lin, int Lout, int pad, int Cout)
{
    constexpr int CI    = (K == 1) ? 32 : 16;   // ci chunk
    constexpr int SPAN  = 63 * S + K;           // staged input span per ci
    constexpr int WN    = 3 * S + K;            // per-thread window
    constexpr int NW4   = (WN + 3) / 4;         // float4s per window
    constexpr int SPANA = (SPAN + 3) & ~3;
    constexpr int REND  = 60 * S + 4 * NW4;     // max vector-read end
    constexpr int SPANP = (SPANA > REND) ? SPANA : REND;
    constexpr int LWP   = 68;                   // lw co-stride (padded)
    constexpr int PER   = (CI / 4) * K;         // weight floats per thread

    __shared__ float lin[CI * SPANP];
    __shared__ float lw[CI * K * LWP];

    const int tid = threadIdx.x;
    const int tx = tid & 15, ty = tid >> 4;
    const int t0 = blockIdx.x * 64;
    const int o0 = blockIdx.y * 64;
    const int b  = blockIdx.z;

    float acc[4][4];
    #pragma unroll
    for (int c = 0; c < 4; ++c) {
        float bv = bias ? bias[o0 + 4 * ty + c] : 0.0f;
        #pragma unroll
        for (int u = 0; u < 4; ++u) acc[c][u] = bv;
    }

    const float* inb = in + (size_t)b * Cin * Lin;
    const int p0 = t0 * S - pad;

    // staging thread roles (pow2 math only)
    constexpr int TPR = 256 / CI;               // threads per input row
    const int sci = tid / TPR, sj0 = tid % TPR;
    const int wco = tid >> 2, wpart = tid & 3;  // 4 threads per co
    const int cibase = wpart * (CI / 4);

    for (int ci0 = 0; ci0 < Cin; ci0 += CI) {
        __syncthreads();
        // ---- stage input rows (coalesced; GN+ReLU fused; zero-fill OOB) ----
        {
            const float* srow = inb + (size_t)(ci0 + sci) * Lin;
            float sc = 0.f, sh = 0.f;
            if (GN) {
                sc = scale[b * Cin + ci0 + sci];
                sh = shift[b * Cin + ci0 + sci];
            }
            for (int j = sj0; j < SPAN; j += TPR) {
                int p = p0 + j;
                bool ok = (p >= 0) && (p < Lin);
                float v = ok ? srow[p] : 0.0f;
                if (GN) v = ok ? fmaxf(v * sc + sh, 0.0f) : 0.0f;
                lin[sci * SPANP + j] = v;
            }
        }
        // ---- stage weights: contiguous float4 per (co,part); static (ci,k) ----
        {
            const float* wsrc = w + (size_t)(o0 + wco) * Cin * K
                                  + (size_t)ci0 * K + wpart * PER;
            #pragma unroll
            for (int e = 0; e < PER / 4; ++e) {
                const float4 v = *(const float4*)(wsrc + 4 * e);
                #pragma unroll
                for (int i = 0; i < 4; ++i) {
                    const int rem = 4 * e + i;          // compile-time after unroll
                    const int cio = rem / K, kk = rem % K;
                    lw[((cibase + cio) * K + kk) * LWP + wco] = ((const float*)&v)[i];
                }
            }
        }
        __syncthreads();

        for (int ci = 0; ci < CI; ++ci) {
            float win[NW4 * 4];
            const float* lrow = &lin[ci * SPANP + 4 * S * tx];
            #pragma unroll
            for (int q = 0; q < NW4; ++q)
                *(float4*)&win[4 * q] = *(const float4*)(lrow + 4 * q);
            #pragma unroll
            for (int k = 0; k < K; ++k) {
                const float4 wv = *(const float4*)&lw[(ci * K + k) * LWP + 4 * ty];
                #pragma unroll
                for (int u = 0; u < 4; ++u) {
                    float x = win[u * S + k];
                    acc[0][u] += x * wv.x;
                    acc[1][u] += x * wv.y;
                    acc[2][u] += x * wv.z;
                    acc[3][u] += x * wv.w;
                }
            }
        }
    }

    // ---- epilogue ----
    if (RESID) {
        #pragma unroll
        for (int c = 0; c < 4; ++c) {
            const float4 rv = *(const float4*)(resid +
                ((size_t)b * Cout + o0 + 4 * ty + c) * Lout + t0 + 4 * tx);
            acc[c][0] += rv.x; acc[c][1] += rv.y; acc[c][2] += rv.z; acc[c][3] += rv.w;
        }
    }
    if (RELU_OUT) {
        #pragma unroll
        for (int c = 0; c < 4; ++c)
            #pragma unroll
            for (int u = 0; u < 4; ++u) acc[c][u] = fmaxf(acc[c][u], 0.f);
    }
    if (TSTORE) {
        // z[(b*L + t)*Cout + d], d = o0+4ty..+3
        #pragma unroll
        for (int u = 0; u < 4; ++u) {
            float4 v; v.x = acc[0][u]; v.y = acc[1][u]; v.z = acc[2][u]; v.w = acc[3][u];
            *(float4*)(out + ((size_t)b * Lout + t0 + 4 * tx + u) * Cout + o0 + 4 * ty) = v;
        }
    } else if (VSTORE) {
        #pragma unroll
        for (int c = 0; c < 4; ++c) {
            float4 v; v.x = acc[c][0]; v.y = acc[c][1]; v.z = acc[c][2]; v.w = acc[c][3];
            *(float4*)(out + ((size_t)b * Cout + o0 + 4 * ty + c) * Lout + t0 + 4 * tx) = v;
        }
    } else {
        #pragma unroll
        for (int c = 0; c < 4; ++c)
            #pragma unroll
            for (int u = 0; u < 4; ++u)
                out[((size_t)b * Cout + o0 + 4 * ty + c) * Lout + t0 + 4 * tx + u] = acc[c][u];
    }
}

// ---------------------------------------------------------------------------
// LDS-tiled ConvTranspose1d stride-2 (parity-split). Block = 64 t2 x 64 co
// for one b. Threads 256 = 16tx(t2) x 16ty(co); thread owns 4 t2 x 4 co ->
// 8 consecutive outputs x 4 co (32 accumulators, even/odd split).
// Same round-7 staging rework as convtile_k. Inner loop keeps the round-6
// one-float4-weight-then-16-FMA shape (low VGPR; round-5's wc[K][4] staging
// gave VGPR=172 / 12% occupancy / 2x regression).
//   K=3 (pad_lo=1): even(t')=w1*x[t'];            odd(t')=w0*x[t']+w2*x[t'+1]
//   K=5 (pad_lo=2): even(t')=w0*x[t'-1]+w2*x[t']+w4*x[t'+1]; odd(t')=w1*x[t']+w3*x[t'+1]
// Per-tap mapping (window offset joff, parity target):
//   K=5: k=0->E win[u]; k=1->O win[u+1]; k=2->E win[u+1]; k=3->O win[u+2]; k=4->E win[u+2]
//   K=3: k=0->O win[u]; k=1->E win[u];   k=2->O win[u+1]
// Fused ReLU; stores two float4 per co ({E0,O0,E1,O1},{E2,O2,E3,O3}).
// ---------------------------------------------------------------------------
template<int K>
__global__ __launch_bounds__(256, 4) void convttile_k(
    const float* __restrict__ in, const float* __restrict__ w,
    const float* __restrict__ bias, float* __restrict__ out,
    int Cin, int Lin, int Cout)
{
    constexpr int CI    = 16;
    constexpr int SPAN  = (K == 5) ? 66 : 65;   // t2 span incl. halo
    constexpr int SPANP = 68;                   // covers 60 + 8 vector read end
    constexpr int WNl   = (K == 5) ? 6 : 5;     // per-thread window
    constexpr int NW4   = (WNl + 3) / 4;        // = 2
    constexpr int LWP   = 68;
    constexpr int PER   = (CI / 4) * K;

    __shared__ float lin[CI * SPANP];
    __shared__ float lw[CI * K * LWP];

    const int tid = threadIdx.x;
    const int tx = tid & 15, ty = tid >> 4;
    const int t20 = blockIdx.x * 64;
    const int o0  = blockIdx.y * 64;
    const int b   = blockIdx.z;
    const int Lout = 2 * Lin;

    float accE[4][4], accO[4][4];
    #pragma unroll
    for (int c = 0; c < 4; ++c) {
        float bv = bias[o0 + 4 * ty + c];
        #pragma unroll
        for (int u = 0; u < 4; ++u) { accE[c][u] = bv; accO[c][u] = bv; }
    }

    const float* inb = in + (size_t)b * Cin * Lin;
    const int p0 = (K == 5) ? (t20 - 1) : t20;

    constexpr int TPR = 256 / CI;               // 16 threads per input row
    const int sci = tid / TPR, sj0 = tid % TPR;
    const int wco = tid >> 2, wpart = tid & 3;
    const int cibase = wpart * (CI / 4);

    for (int ci0 = 0; ci0 < Cin; ci0 += CI) {
        __syncthreads();
        // ---- stage input rows (zero-fill halo OOB) ----
        {
            const float* srow = inb + (size_t)(ci0 + sci) * Lin;
            for (int j = sj0; j < SPAN; j += TPR) {
                int p = p0 + j;
                bool ok = (p >= 0) && (p < Lin);
                lin[sci * SPANP + j] = ok ? srow[p] : 0.0f;
            }
        }
        // ---- stage weights: contiguous float4 per (co,part); static (ci,k) ----
        {
            const float* wsrc = w + (size_t)(o0 + wco) * Cin * K
                                  + (size_t)ci0 * K + wpart * PER;
            #pragma unroll
            for (int e = 0; e < PER / 4; ++e) {
                const float4 v = *(const float4*)(wsrc + 4 * e);
                #pragma unroll
                for (int i = 0; i < 4; ++i) {
                    const int rem = 4 * e + i;
                    const int cio = rem / K, kk = rem % K;
                    lw[((cibase + cio) * K + kk) * LWP + wco] = ((const float*)&v)[i];
                }
            }
        }
        __syncthreads();

        for (int ci = 0; ci < CI; ++ci) {
            float win[NW4 * 4];
            const float* lrow = &lin[ci * SPANP + 4 * tx];
            #pragma unroll
            for (int q = 0; q < NW4; ++q)
                *(float4*)&win[4 * q] = *(const float4*)(lrow + 4 * q);
            #pragma unroll
            for (int k = 0; k < K; ++k) {
                const float4 wv = *(const float4*)&lw[(ci * K + k) * LWP + 4 * ty];
                const int  joff = (K == 5) ? ((k + 1) >> 1) : (k >> 1);
                const bool toE  = (K == 5) ? ((k & 1) == 0) : (k == 1);
                #pragma unroll
                for (int u = 0; u < 4; ++u) {
                    float x = win[u + joff];
                    if (toE) {
                        accE[0][u] += x * wv.x;
                        accE[1][u] += x * wv.y;
                        accE[2][u] += x * wv.z;
                        accE[3][u] += x * wv.w;
                    } else {
                        accO[0][u] += x * wv.x;
                        accO[1][u] += x * wv.y;
                        accO[2][u] += x * wv.z;
                        accO[3][u] += x * wv.w;
                    }
                }
            }
        }
    }

    // ---- epilogue: ReLU + interleaved even/odd float4 stores ----
    size_t base = ((size_t)b * Cout + o0 + 4 * ty) * (size_t)Lout + (size_t)(2 * (t20 + 4 * tx));
    #pragma unroll
    for (int c = 0; c < 4; ++c) {
        float4 v0, v1;
        v0.x = fmaxf(accE[c][0], 0.f); v0.y = fmaxf(accO[c][0], 0.f);
        v0.z = fmaxf(accE[c][1], 0.f); v0.w = fmaxf(accO[c][1], 0.f);
        v1.x = fmaxf(accE[c][2], 0.f); v1.y = fmaxf(accO[c][2], 0.f);
        v1.z = fmaxf(accE[c][3], 0.f); v1.w = fmaxf(accO[c][3], 0.f);
        *(float4*)(out + base + (size_t)c * Lout)     = v0;
        *(float4*)(out + base + (size_t)c * Lout + 4) = v1;
    }
}

// ---------------------------------------------------------------------------
// GroupNorm stats -> per-(b,c) scale/shift (eps 1e-5)
// ---------------------------------------------------------------------------
__global__ __launch_bounds__(256) void gnstats_k(
    const float* __restrict__ x, const float* __restrict__ g,
    const float* __restrict__ be, float* __restrict__ scale,
    float* __restrict__ shift, int C, int L, int G)
{
    int tid = threadIdx.x;
    int b = blockIdx.x / G, gr = blockIdx.x % G;
    int cpg = C / G;
    size_t n = (size_t)cpg * L;
    const float* base = x + ((size_t)b * C + (size_t)gr * cpg) * L;
    float s = 0.f, s2 = 0.f;
    for (size_t idx = tid; idx < n; idx += 256) { float v = base[idx]; s += v; s2 += v * v; }
    __shared__ float rs[256], rq[256];
    rs[tid] = s; rq[tid] = s2; __syncthreads();
    for (int off = 128; off > 0; off >>= 1) {
        if (tid < off) { rs[tid] += rs[tid + off]; rq[tid] += rq[tid + off]; }
        __syncthreads();
    }
    float mean = rs[0] / (float)n;
    float var  = rq[0] / (float)n - mean * mean;
    float inv  = rsqrtf(var + 1e-5f);
    if (tid < cpg) {
        int c = gr * cpg + tid;
        float ga = g[c], bb = be[c];
        scale[b * C + c] = inv * ga;
        shift[b * C + c] = bb - mean * inv * ga;
    }
}

// ---------------------------------------------------------------------------
// VQ: 64 positions/block, 16 code-tiles of 64, 4x4 register dot tiles.
// ---------------------------------------------------------------------------
__global__ __launch_bounds__(256) void vq_k(
    const float* __restrict__ z,       // [32768,128]
    const float* __restrict__ cb,      // [1024,128]
    float* __restrict__ out_q,         // [B,128,1024]
    float* __restrict__ lossAcc,
    unsigned int* __restrict__ hist,
    int* __restrict__ ip_out)
{
    const int tid = threadIdx.x;
    const int pbase = blockIdx.x * 64;
    __shared__ float zs[64 * 129];
    __shared__ float cbs[64 * 129];
    __shared__ float cn[64];
    __shared__ float rd[256];
    __shared__ int   ri[256];
    __shared__ int   ip[64];

    for (int f = tid; f < 64 * 128; f += 256) {
        int p = f >> 7, d = f & 127;
        zs[p * 129 + d] = z[(size_t)pbase * 128 + f];
    }

    float mind[4]; int minc[4];
    #pragma unroll
    for (int a = 0; a < 4; ++a) { mind[a] = 3.4e38f; minc[a] = 0; }
    const int tp = tid >> 4, tr = tid & 15;
    const int prow = tp * 4, crow = tr * 4;

    for (int ct = 0; ct < 16; ++ct) {
        __syncthreads();
        for (int f = tid; f < 64 * 128; f += 256) {
            int c = f >> 7, d = f & 127;
            cbs[c * 129 + d] = cb[((size_t)ct * 64 + c) * 128 + d];
        }
        __syncthreads();
        if (tid < 64) {
            float s = 0.f;
            for (int d = 0; d < 128; ++d) { float v = cbs[tid * 129 + d]; s += v * v; }
            cn[tid] = s;
        }
        __syncthreads();
        float dot[4][4];
        #pragma unroll
        for (int a = 0; a < 4; ++a)
            #pragma unroll
            for (int e = 0; e < 4; ++e) dot[a][e] = 0.f;
        for (int d = 0; d < 128; ++d) {
            float za[4], cc[4];
            #pragma unroll
            for (int a = 0; a < 4; ++a) za[a] = zs[(prow + a) * 129 + d];
            #pragma unroll
            for (int e = 0; e < 4; ++e) cc[e] = cbs[(crow + e) * 129 + d];
            #pragma unroll
            for (int a = 0; a < 4; ++a)
                #pragma unroll
                for (int e = 0; e < 4; ++e) dot[a][e] += za[a] * cc[e];
        }
        #pragma unroll
        for (int e = 0; e < 4; ++e) {
            int c = ct * 64 + crow + e;
            float cne = cn[crow + e];
            #pragma unroll
            for (int a = 0; a < 4; ++a) {
                float dist = cne - 2.0f * dot[a][e];
                if (dist < mind[a]) { mind[a] = dist; minc[a] = c; }
            }
        }
    }

    for (int a = 0; a < 4; ++a) {
        __syncthreads();
        rd[tid] = mind[a]; ri[tid] = minc[a];
        __syncthreads();
        if (tr == 0) {
            float bd = rd[tid]; int bi = ri[tid];
            for (int u = 1; u < 16; ++u) {
                float dv = rd[tid + u]; int iv = ri[tid + u];
                if (dv < bd || (dv == bd && iv < bi)) { bd = dv; bi = iv; }
            }
            ip[prow + a] = bi;
            atomicAdd(&hist[bi], 1u);
        }
    }
    __syncthreads();

    if (tid < 64) ip_out[pbase + tid] = ip[tid];

    float lp = 0.f;
    for (int f = tid; f < 64 * 128; f += 256) {
        int p = f >> 7, d = f & 127;
        int gp = pbase + p, b = gp >> 10, l = gp & 1023;
        float qv = cb[(size_t)ip[p] * 128 + d];
        float zv = zs[p * 129 + d];
        float df = qv - zv; lp += df * df;
        out_q[(((size_t)b * 128 + d) << 10) + l] = qv;
    }
    rd[tid] = lp; __syncthreads();
    for (int off = 128; off > 0; off >>= 1) {
        if (tid < off) rd[tid] += rd[tid + off];
        __syncthreads();
    }
    if (tid == 0) atomicAdd(lossAcc, rd[0]);
}

// one-hot enc write (fp32) from indices; enc region was scratch until now.
__global__ __launch_bounds__(256) void enc_k(
    const int* __restrict__ ip, float2* __restrict__ enc)
{
    size_t idx = (size_t)blockIdx.x * 256 + threadIdx.x;   // 16,777,216 float2
    int p  = (int)(idx >> 9);
    int q2 = (int)(idx & 511);
    int best = ip[p];
    int c0 = q2 * 2;
    float2 v;
    v.x = (c0     == best) ? 1.0f : 0.0f;
    v.y = (c0 + 1 == best) ? 1.0f : 0.0f;
    enc[idx] = v;
}

// mean over L=1024 of fp32 [B,D,L]; one block per (b,d)
__global__ __launch_bounds__(256) void pool_k(const float* __restrict__ q, float* __restrict__ zp)
{
    int tid = threadIdx.x;
    const float* row = q + (size_t)blockIdx.x * 1024;
    float s = 0.f;
    for (int l = tid; l < 1024; l += 256) s += row[l];
    __shared__ float rs[256];
    rs[tid] = s; __syncthreads();
    for (int off = 128; off > 0; off >>= 1) {
        if (tid < off) rs[tid] += rs[tid + off];
        __syncthreads();
    }
    if (tid == 0) zp[blockIdx.x] = rs[0] * (1.0f / 1024.0f);
}

// behavior MLP head, single block
__global__ __launch_bounds__(256) void beh_k(
    const float* __restrict__ zp,
    const float* __restrict__ w1, const float* __restrict__ b1,
    const float* __restrict__ w2, const float* __restrict__ b2,
    const float* __restrict__ w3, const float* __restrict__ b3,
    float* __restrict__ out)
{
    __shared__ float zs[32 * 128];
    __shared__ float h1s[32 * 128];
    __shared__ float h2s[32 * 64];
    int tid = threadIdx.x;
    for (int f = tid; f < 4096; f += 256) zs[f] = zp[f];
    __syncthreads();
    for (int f = tid; f < 4096; f += 256) {
        int bi = f >> 7, j = f & 127;
        float acc = b1[j];
        for (int d = 0; d < 128; ++d) acc += zs[bi * 128 + d] * w1[j * 128 + d];
        h1s[f] = fmaxf(acc, 0.f);
    }
    __syncthreads();
    for (int f = tid; f < 2048; f += 256) {
        int bi = f >> 6, j = f & 63;
        float acc = b2[j];
        for (int d = 0; d < 128; ++d) acc += h1s[bi * 128 + d] * w2[j * 128 + d];
        h2s[f] = fmaxf(acc, 0.f);
    }
    __syncthreads();
    if (tid < 128) {
        int bi = tid >> 2, j = tid & 3;
        float acc = b3[j];
        for (int d = 0; d < 64; ++d) acc += h2s[bi * 64 + d] * w3[j * 64 + d];
        out[tid] = acc;
    }
}

__global__ __launch_bounds__(1024) void init_k(unsigned int* hist, float* lossAcc)
{
    hist[threadIdx.x] = 0u;
    if (threadIdx.x == 0) *lossAcc = 0.f;
}

__global__ __launch_bounds__(1024) void fin_k(
    const unsigned int* __restrict__ hist, const float* __restrict__ lossAcc,
    float* __restrict__ out_loss, float* __restrict__ out_perp)
{
    __shared__ float rs[1024];
    int tid = threadIdx.x;
    float avg = (float)hist[tid] * (1.0f / 32768.0f);
    rs[tid] = avg * logf(avg + 1e-10f);
    __syncthreads();
    for (int off = 512; off > 0; off >>= 1) {
        if (tid < off) rs[tid] += rs[tid + off];
        __syncthreads();
    }
    if (tid == 0) {
        out_perp[0] = expf(-rs[0]);
        out_loss[0] = 0.25f * lossAcc[0] * (1.0f / 4194304.0f);
    }
}

// ---------------------------------------------------------------------------
extern "C" void kernel_launch(void* const* d_in, const int* in_sizes, int n_in,
                              void* d_out, int out_size, void* d_ws, size_t ws_size,
                              hipStream_t stream)
{
    const float* X    = (const float*)d_in[0];
    const float* e1w  = (const float*)d_in[1];  const float* e1b = (const float*)d_in[2];
    const float* e2w  = (const float*)d_in[3];  const float* e2b = (const float*)d_in[4];
    const float* e3w  = (const float*)d_in[5];  const float* e3b = (const float*)d_in[6];
    const float* r0g1g = (const float*)d_in[7];  const float* r0g1b = (const float*)d_in[8];
    const float* r0c1w = (const float*)d_in[9];
    const float* r0g2g = (const float*)d_in[10]; const float* r0g2b = (const float*)d_in[11];
    const float* r0c2w = (const float*)d_in[12];
    const float* r1g1g = (const float*)d_in[13]; const float* r1g1b = (const float*)d_in[14];
    const float* r1c1w = (const float*)d_in[15];
    const float* r1g2g = (const float*)d_in[16]; const float* r1g2b = (const float*)d_in[17];
    const float* r1c2w = (const float*)d_in[18];
    const float* pvw  = (const float*)d_in[19]; const float* pvb = (const float*)d_in[20];
    const float* CB   = (const float*)d_in[21];
    const float* d1w  = (const float*)d_in[22]; const float* d1b = (const float*)d_in[23];
    const float* d2w  = (const float*)d_in[24]; const float* d2b = (const float*)d_in[25];
    const float* d3w  = (const float*)d_in[26]; const float* d3b = (const float*)d_in[27];
    const float* bh1w = (const float*)d_in[28]; const float* bh1b = (const float*)d_in[29];
    const float* bh2w = (const float*)d_in[30]; const float* bh2b = (const float*)d_in[31];
    const float* bh3w = (const float*)d_in[32]; const float* bh3b = (const float*)d_in[33];

    // ---- output regions (fp32 elements) ----
    float* out = (float*)d_out;
    const size_t N_XREC = 16777216ull, N_Q = 4194304ull, N_ENC = 33554432ull;
    float* out_loss = out;
    float* out_xrec = out + 1;                          // 64 MiB region
    float* out_perp = out + 1 + N_XREC;
    float* out_q    = out + 2 + N_XREC;                 // 16 MiB region
    float* out_enc  = out + 2 + N_XREC + N_Q;           // 128 MiB region
    float* out_beh  = out + 2 + N_XREC + N_Q + N_ENC;

    // ---- scratch staging (serial lifetimes; FULL-B encoder, HALF-B decoder) ----
    // xrec region: h1 (e1 out, 32x128x4096 = 16,777,216 fl) at out+4 (16B-aligned).
    //   Overruns region by 3 floats into {out_perp, out_q[0..1]} - all rewritten
    //   later by vq_k / fin_k. h3 (32x512x1024, same size) aliases h1 (e3 reads
    //   only h2). c2 writes h3 in-place over its own resid read (elementwise).
    float* h1 = out + 4;
    float* h3 = h1;
    // enc region (33,554,432 fl), base A = out_enc+2 (16B-aligned):
    //   encoder phase: h2 [0,16.8M) ; t2q [16.8M,21.0M) ; z [21.0M,25.2M)
    //   decoder phase: d1o [0,16.8M) ; d2o [16.8M,33.6M) (+2 fl into out_beh,
    //   which beh_k writes afterwards). enc_k finally overwrites whole region.
    float* A   = out_enc + 2;
    float* h2  = A;
    float* t2q = A + 16777216;
    float* z   = A + 20971520;
    float* d1o = A;
    float* d2o = A + 16777216;

    // ---- d_ws: smalls ONLY (~320 KB) ----
    float* W = (float*)d_ws;
    float* lossA = W;                              // 1 (+pad 16)
    unsigned int* hist = (unsigned int*)(W + 16);  // 1,024
    float* zp   = W + 16 + 1024;                   // 4,096
    int* ipArr  = (int*)(W + 16 + 1024 + 4096);    // 32,768
    float* scA  = W + 16 + 1024 + 4096 + 32768;    // 16,384 (32 b x 512)
    float* shA  = scA + 16384;                     // 16,384
    float* scB  = shA + 16384;                     // 4,096 (32 b x 128)
    float* shB  = scB + 4096;                      // 4,096

    init_k<<<dim3(1), dim3(1024), 0, stream>>>(hist, lossA);

    // ---- encoder (full batch B=32) ----
    // e1: K7 s1 p3, 128->128, L4096
    convtile_k<7,1,false,false,true,false,true><<<dim3(64, 2, 32), 256, 0, stream>>>(
        X, e1w, e1b, h1, nullptr, nullptr, nullptr, 128, 4096, 4096, 3, 128);
    // e2: K5 s2 p2, 128->256, L4096->2048
    convtile_k<5,2,false,false,true,false,true><<<dim3(32, 4, 32), 256, 0, stream>>>(
        h1, e2w, e2b, h2, nullptr, nullptr, nullptr, 128, 4096, 2048, 2, 256);
    // e3: K3 s2 p1, 256->512, 2048->1024 (writes h3, aliasing h1; reads only h2)
    convtile_k<3,2,false,false,false,false,true><<<dim3(16, 8, 32), 256, 0, stream>>>(
        h2, e3w, e3b, h3, nullptr, nullptr, nullptr, 256, 2048, 1024, 1, 512);

    // res block 0
    gnstats_k<<<dim3(256), 256, 0, stream>>>(h3, r0g1g, r0g1b, scA, shA, 512, 1024, 8);
    convtile_k<3,1,true,false,false,false,true><<<dim3(16, 2, 32), 256, 0, stream>>>(
        h3, r0c1w, nullptr, t2q, scA, shA, nullptr, 512, 1024, 1024, 1, 128);
    gnstats_k<<<dim3(256), 256, 0, stream>>>(t2q, r0g2g, r0g2b, scB, shB, 128, 1024, 8);
    convtile_k<1,1,true,true,false,false,true><<<dim3(16, 8, 32), 256, 0, stream>>>(
        t2q, r0c2w, nullptr, h3, scB, shB, h3, 128, 1024, 1024, 0, 512);

    // res block 1
    gnstats_k<<<dim3(256), 256, 0, stream>>>(h3, r1g1g, r1g1b, scA, shA, 512, 1024, 8);
    convtile_k<3,1,true,false,false,false,true><<<dim3(16, 2, 32), 256, 0, stream>>>(
        h3, r1c1w, nullptr, t2q, scA, shA, nullptr, 512, 1024, 1024, 1, 128);
    gnstats_k<<<dim3(256), 256, 0, stream>>>(t2q, r1g2g, r1g2b, scB, shB, 128, 1024, 8);
    convtile_k<1,1,true,true,false,false,true><<<dim3(16, 8, 32), 256, 0, stream>>>(
        t2q, r1c2w, nullptr, h3, scB, shB, h3, 128, 1024, 1024, 0, 512);

    // pre-VQ 1x1 conv 512->128, transposed store -> z [pos,128]
    convtile_k<1,1,false,false,false,true,true><<<dim3(16, 2, 32), 256, 0, stream>>>(
        h3, pvw, pvb, z, nullptr, nullptr, nullptr, 512, 1024, 1024, 0, 128);

    // ---- VQ: writes out_q (final fp32), hist, loss, indices ----
    vq_k<<<dim3(512), 256, 0, stream>>>(z, CB, out_q, lossA, hist, ipArr);

    // ---- decoder, per batch-HALF (16 samples); LDS-tiled transpose convs ----
    for (int h = 0; h < 2; ++h) {
        convttile_k<3><<<dim3(16, 8, 16), 256, 0, stream>>>(
            out_q + (size_t)h * 2097152, d1w, d1b, d1o, 128, 1024, 512);
        convttile_k<5><<<dim3(32, 4, 16), 256, 0, stream>>>(
            d1o, d2w, d2b, d2o, 512, 2048, 256);
        convtile_k<7,1,false,false,false,false,false><<<dim3(64, 2, 16), 256, 0, stream>>>(
            d2o, d3w, d3b, out_xrec + (size_t)h * 8388608, nullptr, nullptr, nullptr,
            256, 4096, 4096, 3, 128);
    }

    // ---- behavior head (after decoder: d2o overhangs 2 floats into out_beh) ----
    pool_k<<<dim3(4096), 256, 0, stream>>>(out_q, zp);
    beh_k<<<dim3(1), 256, 0, stream>>>(zp, bh1w, bh1b, bh2w, bh2b, bh3w, bh3b, out_beh);

    // ---- one-hot enc (overwrites enc-region scratch with the real output) ----
    enc_k<<<dim3(65536), 256, 0, stream>>>(ipArr, (float2*)out_enc);

    // ---- loss + perplexity ----
    fin_k<<<dim3(1), 1024, 0, stream>>>(hist, lossA, out_loss, out_perp);
}

// Round 8
// 4471.021 us; speedup vs baseline: 2.9799x; 1.0385x over previous
//
#include <hip/hip_runtime.h>

// All tensors fp32 (per the reference: inputs, weights, outputs all float32).

// ---------------------------------------------------------------------------
// LDS-tiled direct conv1d ("implicit GEMM"). Block = 64 co x (16*TT) t for
// one b. Threads 256 = 16tx(t) x 16ty(co); each thread 4co x TT t register
// tile. Staging: input rows cooperatively (1 row / 16-thread group, pow2
// index math, GN scale hoisted); weights via 4-threads-per-co contiguous
// float4 loads with compile-time (ci,k) split (no div/mod). lw stride 68 and
// lin stride pad keep LDS traffic <=2-way bank-aliased (free). win as float4s.
// TT=8 for K7 layers: 224 FMA per 11 ds_read per ci (TT=4: 112 per 10).
//   TSTORE: write transposed [pos][co] layout (pre-VQ z).
//   VSTORE: float4 stores (dst 16B-aligned); else scalar stores.
// ---------------------------------------------------------------------------
template<int K, int S, int TT, bool GN, bool RESID, bool RELU_OUT, bool TSTORE, bool VSTORE>
__global__ __launch_bounds__(256, 4) void convtile_k(
    const float* __restrict__ in, const float* __restrict__ w,
    const float* __restrict__ bias, float* __restrict__ out,
    const float* __restrict__ scale, const float* __restrict__ shift,
    const float* __restrict__ resid,
    int Cin, int Lin, int Lout, int pad, int Cout)
{
    constexpr int CI    = (K == 1) ? 32 : 16;   // ci chunk
    constexpr int BT    = 16 * TT;              // t per block
    constexpr int SPAN  = (BT - 1) * S + K;     // staged input span per ci
    constexpr int WN    = (TT - 1) * S + K;     // per-thread window
    constexpr int NW4   = (WN + 3) / 4;         // float4s per window
    constexpr int SPANA = (SPAN + 3) & ~3;
    constexpr int REND  = 15 * TT * S + 4 * NW4;  // max vector-read end
    constexpr int SPANP = (SPANA > REND) ? SPANA : REND;
    constexpr int LWP   = 68;                   // lw co-stride (padded)
    constexpr int PER   = (CI / 4) * K;         // weight floats per thread
    constexpr int NQ    = TT / 4;               // float4s per co on store

    __shared__ float lin[CI * SPANP];
    __shared__ float lw[CI * K * LWP];

    const int tid = threadIdx.x;
    const int tx = tid & 15, ty = tid >> 4;
    const int t0 = blockIdx.x * BT;
    const int o0 = blockIdx.y * 64;
    const int b  = blockIdx.z;

    float acc[4][TT];
    #pragma unroll
    for (int c = 0; c < 4; ++c) {
        float bv = bias ? bias[o0 + 4 * ty + c] : 0.0f;
        #pragma unroll
        for (int u = 0; u < TT; ++u) acc[c][u] = bv;
    }

    const float* inb = in + (size_t)b * Cin * Lin;
    const int p0 = t0 * S - pad;

    // staging thread roles (pow2 math only)
    constexpr int TPR = 256 / CI;               // threads per input row
    const int sci = tid / TPR, sj0 = tid % TPR;
    const int wco = tid >> 2, wpart = tid & 3;  // 4 threads per co
    const int cibase = wpart * (CI / 4);

    for (int ci0 = 0; ci0 < Cin; ci0 += CI) {
        __syncthreads();
        // ---- stage input rows (coalesced; GN+ReLU fused; zero-fill OOB) ----
        {
            const float* srow = inb + (size_t)(ci0 + sci) * Lin;
            float sc = 0.f, sh = 0.f;
            if (GN) {
                sc = scale[b * Cin + ci0 + sci];
                sh = shift[b * Cin + ci0 + sci];
            }
            for (int j = sj0; j < SPAN; j += TPR) {
                int p = p0 + j;
                bool ok = (p >= 0) && (p < Lin);
                float v = ok ? srow[p] : 0.0f;
                if (GN) v = ok ? fmaxf(v * sc + sh, 0.0f) : 0.0f;
                lin[sci * SPANP + j] = v;
            }
        }
        // ---- stage weights: contiguous float4 per (co,part); static (ci,k) ----
        {
            const float* wsrc = w + (size_t)(o0 + wco) * Cin * K
                                  + (size_t)ci0 * K + wpart * PER;
            #pragma unroll
            for (int e = 0; e < PER / 4; ++e) {
                const float4 v = *(const float4*)(wsrc + 4 * e);
                #pragma unroll
                for (int i = 0; i < 4; ++i) {
                    const int rem = 4 * e + i;          // compile-time after unroll
                    const int cio = rem / K, kk = rem % K;
                    lw[((cibase + cio) * K + kk) * LWP + wco] = ((const float*)&v)[i];
                }
            }
        }
        __syncthreads();

        for (int ci = 0; ci < CI; ++ci) {
            float win[NW4 * 4];
            const float* lrow = &lin[ci * SPANP + TT * S * tx];
            #pragma unroll
            for (int q = 0; q < NW4; ++q)
                *(float4*)&win[4 * q] = *(const float4*)(lrow + 4 * q);
            #pragma unroll
            for (int k = 0; k < K; ++k) {
                const float4 wv = *(const float4*)&lw[(ci * K + k) * LWP + 4 * ty];
                #pragma unroll
                for (int u = 0; u < TT; ++u) {
                    float x = win[u * S + k];
                    acc[0][u] += x * wv.x;
                    acc[1][u] += x * wv.y;
                    acc[2][u] += x * wv.z;
                    acc[3][u] += x * wv.w;
                }
            }
        }
    }

    // ---- epilogue ----
    if (RESID) {
        #pragma unroll
        for (int c = 0; c < 4; ++c)
            #pragma unroll
            for (int q = 0; q < NQ; ++q) {
                const float4 rv = *(const float4*)(resid +
                    ((size_t)b * Cout + o0 + 4 * ty + c) * Lout + t0 + TT * tx + 4 * q);
                acc[c][4*q+0] += rv.x; acc[c][4*q+1] += rv.y;
                acc[c][4*q+2] += rv.z; acc[c][4*q+3] += rv.w;
            }
    }
    if (RELU_OUT) {
        #pragma unroll
        for (int c = 0; c < 4; ++c)
            #pragma unroll
            for (int u = 0; u < TT; ++u) acc[c][u] = fmaxf(acc[c][u], 0.f);
    }
    if (TSTORE) {
        // z[(b*L + t)*Cout + d], d = o0+4ty..+3
        #pragma unroll
        for (int u = 0; u < TT; ++u) {
            float4 v; v.x = acc[0][u]; v.y = acc[1][u]; v.z = acc[2][u]; v.w = acc[3][u];
            *(float4*)(out + ((size_t)b * Lout + t0 + TT * tx + u) * Cout + o0 + 4 * ty) = v;
        }
    } else if (VSTORE) {
        #pragma unroll
        for (int c = 0; c < 4; ++c)
            #pragma unroll
            for (int q = 0; q < NQ; ++q) {
                float4 v;
                v.x = acc[c][4*q+0]; v.y = acc[c][4*q+1];
                v.z = acc[c][4*q+2]; v.w = acc[c][4*q+3];
                *(float4*)(out + ((size_t)b * Cout + o0 + 4 * ty + c) * Lout
                           + t0 + TT * tx + 4 * q) = v;
            }
    } else {
        #pragma unroll
        for (int c = 0; c < 4; ++c)
            #pragma unroll
            for (int u = 0; u < TT; ++u)
                out[((size_t)b * Cout + o0 + 4 * ty + c) * Lout + t0 + TT * tx + u] = acc[c][u];
    }
}

// ---------------------------------------------------------------------------
// LDS-tiled ConvTranspose1d stride-2 (parity-split). Block = (16*TT) t2 x
// 64 co for one b. Threads 256 = 16tx(t2) x 16ty(co); thread owns TT t2 x
// 4 co -> 2*TT consecutive outputs x 4 co (8*TT accumulators, even/odd).
// Inner loop keeps the one-float4-weight-then-FMA shape (low VGPR; round-5's
// wc[K][4] staging gave VGPR=172 / 12% occupancy / 2x regression).
//   K=3 (pad_lo=1): even(t')=w1*x[t'];            odd(t')=w0*x[t']+w2*x[t'+1]
//   K=5 (pad_lo=2): even(t')=w0*x[t'-1]+w2*x[t']+w4*x[t'+1]; odd(t')=w1*x[t']+w3*x[t'+1]
// Per-tap mapping (window offset joff, parity target):
//   K=5: k=0->E win[u]; k=1->O win[u+1]; k=2->E win[u+1]; k=3->O win[u+2]; k=4->E win[u+2]
//   K=3: k=0->O win[u]; k=1->E win[u];   k=2->O win[u+1]
// Fused ReLU; interleaved even/odd float4 stores.
// ---------------------------------------------------------------------------
template<int K, int TT>
__global__ __launch_bounds__(256, 4) void convttile_k(
    const float* __restrict__ in, const float* __restrict__ w,
    const float* __restrict__ bias, float* __restrict__ out,
    int Cin, int Lin, int Cout)
{
    constexpr int CI    = 16;
    constexpr int BT    = 16 * TT;              // t2 per block
    constexpr int HALO  = (K == 5) ? 2 : 1;
    constexpr int SPAN  = BT + HALO;            // t2 span incl. halo
    constexpr int WNl   = TT + HALO;            // per-thread window
    constexpr int NW4   = (WNl + 3) / 4;
    constexpr int SPANA = (SPAN + 3) & ~3;
    constexpr int REND  = 15 * TT + 4 * NW4;
    constexpr int SPANP = (SPANA > REND) ? SPANA : REND;
    constexpr int LWP   = 68;
    constexpr int PER   = (CI / 4) * K;

    __shared__ float lin[CI * SPANP];
    __shared__ float lw[CI * K * LWP];

    const int tid = threadIdx.x;
    const int tx = tid & 15, ty = tid >> 4;
    const int t20 = blockIdx.x * BT;
    const int o0  = blockIdx.y * 64;
    const int b   = blockIdx.z;
    const int Lout = 2 * Lin;

    float accE[4][TT], accO[4][TT];
    #pragma unroll
    for (int c = 0; c < 4; ++c) {
        float bv = bias[o0 + 4 * ty + c];
        #pragma unroll
        for (int u = 0; u < TT; ++u) { accE[c][u] = bv; accO[c][u] = bv; }
    }

    const float* inb = in + (size_t)b * Cin * Lin;
    const int p0 = (K == 5) ? (t20 - 1) : t20;

    constexpr int TPR = 256 / CI;               // 16 threads per input row
    const int sci = tid / TPR, sj0 = tid % TPR;
    const int wco = tid >> 2, wpart = tid & 3;
    const int cibase = wpart * (CI / 4);

    for (int ci0 = 0; ci0 < Cin; ci0 += CI) {
        __syncthreads();
        // ---- stage input rows (zero-fill halo OOB) ----
        {
            const float* srow = inb + (size_t)(ci0 + sci) * Lin;
            for (int j = sj0; j < SPAN; j += TPR) {
                int p = p0 + j;
                bool ok = (p >= 0) && (p < Lin);
                lin[sci * SPANP + j] = ok ? srow[p] : 0.0f;
            }
        }
        // ---- stage weights: contiguous float4 per (co,part); static (ci,k) ----
        {
            const float* wsrc = w + (size_t)(o0 + wco) * Cin * K
                                  + (size_t)ci0 * K + wpart * PER;
            #pragma unroll
            for (int e = 0; e < PER / 4; ++e) {
                const float4 v = *(const float4*)(wsrc + 4 * e);
                #pragma unroll
                for (int i = 0; i < 4; ++i) {
                    const int rem = 4 * e + i;
                    const int cio = rem / K, kk = rem % K;
                    lw[((cibase + cio) * K + kk) * LWP + wco] = ((const float*)&v)[i];
                }
            }
        }
        __syncthreads();

        for (int ci = 0; ci < CI; ++ci) {
            float win[NW4 * 4];
            const float* lrow = &lin[ci * SPANP + TT * tx];
            #pragma unroll
            for (int q = 0; q < NW4; ++q)
                *(float4*)&win[4 * q] = *(const float4*)(lrow + 4 * q);
            #pragma unroll
            for (int k = 0; k < K; ++k) {
                const float4 wv = *(const float4*)&lw[(ci * K + k) * LWP + 4 * ty];
                const int  joff = (K == 5) ? ((k + 1) >> 1) : (k >> 1);
                const bool toE  = (K == 5) ? ((k & 1) == 0) : (k == 1);
                #pragma unroll
                for (int u = 0; u < TT; ++u) {
                    float x = win[u + joff];
                    if (toE) {
                        accE[0][u] += x * wv.x;
                        accE[1][u] += x * wv.y;
                        accE[2][u] += x * wv.z;
                        accE[3][u] += x * wv.w;
                    } else {
                        accO[0][u] += x * wv.x;
                        accO[1][u] += x * wv.y;
                        accO[2][u] += x * wv.z;
                        accO[3][u] += x * wv.w;
                    }
                }
            }
        }
    }

    // ---- epilogue: ReLU + interleaved even/odd float4 stores ----
    size_t base = ((size_t)b * Cout + o0 + 4 * ty) * (size_t)Lout + (size_t)(2 * (t20 + TT * tx));
    #pragma unroll
    for (int c = 0; c < 4; ++c) {
        #pragma unroll
        for (int q = 0; q < TT / 2; ++q) {
            float4 v;
            v.x = fmaxf(accE[c][2*q],   0.f); v.y = fmaxf(accO[c][2*q],   0.f);
            v.z = fmaxf(accE[c][2*q+1], 0.f); v.w = fmaxf(accO[c][2*q+1], 0.f);
            *(float4*)(out + base + (size_t)c * Lout + 4 * q) = v;
        }
    }
}

// ---------------------------------------------------------------------------
// GroupNorm stats -> per-(b,c) scale/shift (eps 1e-5)
// ---------------------------------------------------------------------------
__global__ __launch_bounds__(256) void gnstats_k(
    const float* __restrict__ x, const float* __restrict__ g,
    const float* __restrict__ be, float* __restrict__ scale,
    float* __restrict__ shift, int C, int L, int G)
{
    int tid = threadIdx.x;
    int b = blockIdx.x / G, gr = blockIdx.x % G;
    int cpg = C / G;
    size_t n = (size_t)cpg * L;
    const float* base = x + ((size_t)b * C + (size_t)gr * cpg) * L;
    float s = 0.f, s2 = 0.f;
    for (size_t idx = tid; idx < n; idx += 256) { float v = base[idx]; s += v; s2 += v * v; }
    __shared__ float rs[256], rq[256];
    rs[tid] = s; rq[tid] = s2; __syncthreads();
    for (int off = 128; off > 0; off >>= 1) {
        if (tid < off) { rs[tid] += rs[tid + off]; rq[tid] += rq[tid + off]; }
        __syncthreads();
    }
    float mean = rs[0] / (float)n;
    float var  = rq[0] / (float)n - mean * mean;
    float inv  = rsqrtf(var + 1e-5f);
    if (tid < cpg) {
        int c = gr * cpg + tid;
        float ga = g[c], bb = be[c];
        scale[b * C + c] = inv * ga;
        shift[b * C + c] = bb - mean * inv * ga;
    }
}

// ---------------------------------------------------------------------------
// VQ: 64 positions/block, 16 code-tiles of 64, 4x4 register dot tiles.
// ---------------------------------------------------------------------------
__global__ __launch_bounds__(256) void vq_k(
    const float* __restrict__ z,       // [32768,128]
    const float* __restrict__ cb,      // [1024,128]
    float* __restrict__ out_q,         // [B,128,1024]
    float* __restrict__ lossAcc,
    unsigned int* __restrict__ hist,
    int* __restrict__ ip_out)
{
    const int tid = threadIdx.x;
    const int pbase = blockIdx.x * 64;
    __shared__ float zs[64 * 129];
    __shared__ float cbs[64 * 129];
    __shared__ float cn[64];
    __shared__ float rd[256];
    __shared__ int   ri[256];
    __shared__ int   ip[64];

    for (int f = tid; f < 64 * 128; f += 256) {
        int p = f >> 7, d = f & 127;
        zs[p * 129 + d] = z[(size_t)pbase * 128 + f];
    }

    float mind[4]; int minc[4];
    #pragma unroll
    for (int a = 0; a < 4; ++a) { mind[a] = 3.4e38f; minc[a] = 0; }
    const int tp = tid >> 4, tr = tid & 15;
    const int prow = tp * 4, crow = tr * 4;

    for (int ct = 0; ct < 16; ++ct) {
        __syncthreads();
        for (int f = tid; f < 64 * 128; f += 256) {
            int c = f >> 7, d = f & 127;
            cbs[c * 129 + d] = cb[((size_t)ct * 64 + c) * 128 + d];
        }
        __syncthreads();
        if (tid < 64) {
            float s = 0.f;
            for (int d = 0; d < 128; ++d) { float v = cbs[tid * 129 + d]; s += v * v; }
            cn[tid] = s;
        }
        __syncthreads();
        float dot[4][4];
        #pragma unroll
        for (int a = 0; a < 4; ++a)
            #pragma unroll
            for (int e = 0; e < 4; ++e) dot[a][e] = 0.f;
        for (int d = 0; d < 128; ++d) {
            float za[4], cc[4];
            #pragma unroll
            for (int a = 0; a < 4; ++a) za[a] = zs[(prow + a) * 129 + d];
            #pragma unroll
            for (int e = 0; e < 4; ++e) cc[e] = cbs[(crow + e) * 129 + d];
            #pragma unroll
            for (int a = 0; a < 4; ++a)
                #pragma unroll
                for (int e = 0; e < 4; ++e) dot[a][e] += za[a] * cc[e];
        }
        #pragma unroll
        for (int e = 0; e < 4; ++e) {
            int c = ct * 64 + crow + e;
            float cne = cn[crow + e];
            #pragma unroll
            for (int a = 0; a < 4; ++a) {
                float dist = cne - 2.0f * dot[a][e];
                if (dist < mind[a]) { mind[a] = dist; minc[a] = c; }
            }
        }
    }

    for (int a = 0; a < 4; ++a) {
        __syncthreads();
        rd[tid] = mind[a]; ri[tid] = minc[a];
        __syncthreads();
        if (tr == 0) {
            float bd = rd[tid]; int bi = ri[tid];
            for (int u = 1; u < 16; ++u) {
                float dv = rd[tid + u]; int iv = ri[tid + u];
                if (dv < bd || (dv == bd && iv < bi)) { bd = dv; bi = iv; }
            }
            ip[prow + a] = bi;
            atomicAdd(&hist[bi], 1u);
        }
    }
    __syncthreads();

    if (tid < 64) ip_out[pbase + tid] = ip[tid];

    float lp = 0.f;
    for (int f = tid; f < 64 * 128; f += 256) {
        int p = f >> 7, d = f & 127;
        int gp = pbase + p, b = gp >> 10, l = gp & 1023;
        float qv = cb[(size_t)ip[p] * 128 + d];
        float zv = zs[p * 129 + d];
        float df = qv - zv; lp += df * df;
        out_q[(((size_t)b * 128 + d) << 10) + l] = qv;
    }
    rd[tid] = lp; __syncthreads();
    for (int off = 128; off > 0; off >>= 1) {
        if (tid < off) rd[tid] += rd[tid + off];
        __syncthreads();
    }
    if (tid == 0) atomicAdd(lossAcc, rd[0]);
}

// one-hot enc write (fp32) from indices; enc region was scratch until now.
__global__ __launch_bounds__(256) void enc_k(
    const int* __restrict__ ip, float2* __restrict__ enc)
{
    size_t idx = (size_t)blockIdx.x * 256 + threadIdx.x;   // 16,777,216 float2
    int p  = (int)(idx >> 9);
    int q2 = (int)(idx & 511);
    int best = ip[p];
    int c0 = q2 * 2;
    float2 v;
    v.x = (c0     == best) ? 1.0f : 0.0f;
    v.y = (c0 + 1 == best) ? 1.0f : 0.0f;
    enc[idx] = v;
}

// mean over L=1024 of fp32 [B,D,L]; one block per (b,d)
__global__ __launch_bounds__(256) void pool_k(const float* __restrict__ q, float* __restrict__ zp)
{
    int tid = threadIdx.x;
    const float* row = q + (size_t)blockIdx.x * 1024;
    float s = 0.f;
    for (int l = tid; l < 1024; l += 256) s += row[l];
    __shared__ float rs[256];
    rs[tid] = s; __syncthreads();
    for (int off = 128; off > 0; off >>= 1) {
        if (tid < off) rs[tid] += rs[tid + off];
        __syncthreads();
    }
    if (tid == 0) zp[blockIdx.x] = rs[0] * (1.0f / 1024.0f);
}

// behavior MLP head, single block
__global__ __launch_bounds__(256) void beh_k(
    const float* __restrict__ zp,
    const float* __restrict__ w1, const float* __restrict__ b1,
    const float* __restrict__ w2, const float* __restrict__ b2,
    const float* __restrict__ w3, const float* __restrict__ b3,
    float* __restrict__ out)
{
    __shared__ float zs[32 * 128];
    __shared__ float h1s[32 * 128];
    __shared__ float h2s[32 * 64];
    int tid = threadIdx.x;
    for (int f = tid; f < 4096; f += 256) zs[f] = zp[f];
    __syncthreads();
    for (int f = tid; f < 4096; f += 256) {
        int bi = f >> 7, j = f & 127;
        float acc = b1[j];
        for (int d = 0; d < 128; ++d) acc += zs[bi * 128 + d] * w1[j * 128 + d];
        h1s[f] = fmaxf(acc, 0.f);
    }
    __syncthreads();
    for (int f = tid; f < 2048; f += 256) {
        int bi = f >> 6, j = f & 63;
        float acc = b2[j];
        for (int d = 0; d < 128; ++d) acc += h1s[bi * 128 + d] * w2[j * 128 + d];
        h2s[f] = fmaxf(acc, 0.f);
    }
    __syncthreads();
    if (tid < 128) {
        int bi = tid >> 2, j = tid & 3;
        float acc = b3[j];
        for (int d = 0; d < 64; ++d) acc += h2s[bi * 64 + d] * w3[j * 64 + d];
        out[tid] = acc;
    }
}

__global__ __launch_bounds__(1024) void init_k(unsigned int* hist, float* lossAcc)
{
    hist[threadIdx.x] = 0u;
    if (threadIdx.x == 0) *lossAcc = 0.f;
}

__global__ __launch_bounds__(1024) void fin_k(
    const unsigned int* __restrict__ hist, const float* __restrict__ lossAcc,
    float* __restrict__ out_loss, float* __restrict__ out_perp)
{
    __shared__ float rs[1024];
    int tid = threadIdx.x;
    float avg = (float)hist[tid] * (1.0f / 32768.0f);
    rs[tid] = avg * logf(avg + 1e-10f);
    __syncthreads();
    for (int off = 512; off > 0; off >>= 1) {
        if (tid < off) rs[tid] += rs[tid + off];
        __syncthreads();
    }
    if (tid == 0) {
        out_perp[0] = expf(-rs[0]);
        out_loss[0] = 0.25f * lossAcc[0] * (1.0f / 4194304.0f);
    }
}

// ---------------------------------------------------------------------------
extern "C" void kernel_launch(void* const* d_in, const int* in_sizes, int n_in,
                              void* d_out, int out_size, void* d_ws, size_t ws_size,
                              hipStream_t stream)
{
    const float* X    = (const float*)d_in[0];
    const float* e1w  = (const float*)d_in[1];  const float* e1b = (const float*)d_in[2];
    const float* e2w  = (const float*)d_in[3];  const float* e2b = (const float*)d_in[4];
    const float* e3w  = (const float*)d_in[5];  const float* e3b = (const float*)d_in[6];
    const float* r0g1g = (const float*)d_in[7];  const float* r0g1b = (const float*)d_in[8];
    const float* r0c1w = (const float*)d_in[9];
    const float* r0g2g = (const float*)d_in[10]; const float* r0g2b = (const float*)d_in[11];
    const float* r0c2w = (const float*)d_in[12];
    const float* r1g1g = (const float*)d_in[13]; const float* r1g1b = (const float*)d_in[14];
    const float* r1c1w = (const float*)d_in[15];
    const float* r1g2g = (const float*)d_in[16]; const float* r1g2b = (const float*)d_in[17];
    const float* r1c2w = (const float*)d_in[18];
    const float* pvw  = (const float*)d_in[19]; const float* pvb = (const float*)d_in[20];
    const float* CB   = (const float*)d_in[21];
    const float* d1w  = (const float*)d_in[22]; const float* d1b = (const float*)d_in[23];
    const float* d2w  = (const float*)d_in[24]; const float* d2b = (const float*)d_in[25];
    const float* d3w  = (const float*)d_in[26]; const float* d3b = (const float*)d_in[27];
    const float* bh1w = (const float*)d_in[28]; const float* bh1b = (const float*)d_in[29];
    const float* bh2w = (const float*)d_in[30]; const float* bh2b = (const float*)d_in[31];
    const float* bh3w = (const float*)d_in[32]; const float* bh3b = (const float*)d_in[33];

    // ---- output regions (fp32 elements) ----
    float* out = (float*)d_out;
    const size_t N_XREC = 16777216ull, N_Q = 4194304ull, N_ENC = 33554432ull;
    float* out_loss = out;
    float* out_xrec = out + 1;                          // 64 MiB region
    float* out_perp = out + 1 + N_XREC;
    float* out_q    = out + 2 + N_XREC;                 // 16 MiB region
    float* out_enc  = out + 2 + N_XREC + N_Q;           // 128 MiB region
    float* out_beh  = out + 2 + N_XREC + N_Q + N_ENC;

    // ---- scratch staging (serial lifetimes; FULL-B encoder, HALF-B decoder) ----
    // xrec region: h1 (e1 out, 32x128x4096 = 16,777,216 fl) at out+4 (16B-aligned).
    //   Overruns region by 3 floats into {out_perp, out_q[0..1]} - all rewritten
    //   later by vq_k / fin_k. h3 (32x512x1024, same size) aliases h1 (e3 reads
    //   only h2). c2 writes h3 in-place over its own resid read (elementwise).
    float* h1 = out + 4;
    float* h3 = h1;
    // enc region (33,554,432 fl), base A = out_enc+2 (16B-aligned):
    //   encoder phase: h2 [0,16.8M) ; t2q [16.8M,21.0M) ; z [21.0M,25.2M)
    //   decoder phase: d1o [0,16.8M) ; d2o [16.8M,33.6M) (+2 fl into out_beh,
    //   which beh_k writes afterwards). enc_k finally overwrites whole region.
    float* A   = out_enc + 2;
    float* h2  = A;
    float* t2q = A + 16777216;
    float* z   = A + 20971520;
    float* d1o = A;
    float* d2o = A + 16777216;

    // ---- d_ws: smalls ONLY (~320 KB) ----
    float* W = (float*)d_ws;
    float* lossA = W;                              // 1 (+pad 16)
    unsigned int* hist = (unsigned int*)(W + 16);  // 1,024
    float* zp   = W + 16 + 1024;                   // 4,096
    int* ipArr  = (int*)(W + 16 + 1024 + 4096);    // 32,768
    float* scA  = W + 16 + 1024 + 4096 + 32768;    // 16,384 (32 b x 512)
    float* shA  = scA + 16384;                     // 16,384
    float* scB  = shA + 16384;                     // 4,096 (32 b x 128)
    float* shB  = scB + 4096;                      // 4,096

    init_k<<<dim3(1), dim3(1024), 0, stream>>>(hist, lossA);

    // ---- encoder (full batch B=32) ----
    // e1: K7 s1 p3, 128->128, L4096. TT=8 (128 t/block).
    convtile_k<7,1,8,false,false,true,false,true><<<dim3(32, 2, 32), 256, 0, stream>>>(
        X, e1w, e1b, h1, nullptr, nullptr, nullptr, 128, 4096, 4096, 3, 128);
    // e2: K5 s2 p2, 128->256, L4096->2048
    convtile_k<5,2,4,false,false,true,false,true><<<dim3(32, 4, 32), 256, 0, stream>>>(
        h1, e2w, e2b, h2, nullptr, nullptr, nullptr, 128, 4096, 2048, 2, 256);
    // e3: K3 s2 p1, 256->512, 2048->1024 (writes h3, aliasing h1; reads only h2)
    convtile_k<3,2,4,false,false,false,false,true><<<dim3(16, 8, 32), 256, 0, stream>>>(
        h2, e3w, e3b, h3, nullptr, nullptr, nullptr, 256, 2048, 1024, 1, 512);

    // res block 0
    gnstats_k<<<dim3(256), 256, 0, stream>>>(h3, r0g1g, r0g1b, scA, shA, 512, 1024, 8);
    convtile_k<3,1,4,true,false,false,false,true><<<dim3(16, 2, 32), 256, 0, stream>>>(
        h3, r0c1w, nullptr, t2q, scA, shA, nullptr, 512, 1024, 1024, 1, 128);
    gnstats_k<<<dim3(256), 256, 0, stream>>>(t2q, r0g2g, r0g2b, scB, shB, 128, 1024, 8);
    convtile_k<1,1,4,true,true,false,false,true><<<dim3(16, 8, 32), 256, 0, stream>>>(
        t2q, r0c2w, nullptr, h3, scB, shB, h3, 128, 1024, 1024, 0, 512);

    // res block 1
    gnstats_k<<<dim3(256), 256, 0, stream>>>(h3, r1g1g, r1g1b, scA, shA, 512, 1024, 8);
    convtile_k<3,1,4,true,false,false,false,true><<<dim3(16, 2, 32), 256, 0, stream>>>(
        h3, r1c1w, nullptr, t2q, scA, shA, nullptr, 512, 1024, 1024, 1, 128);
    gnstats_k<<<dim3(256), 256, 0, stream>>>(t2q, r1g2g, r1g2b, scB, shB, 128, 1024, 8);
    convtile_k<1,1,4,true,true,false,false,true><<<dim3(16, 8, 32), 256, 0, stream>>>(
        t2q, r1c2w, nullptr, h3, scB, shB, h3, 128, 1024, 1024, 0, 512);

    // pre-VQ 1x1 conv 512->128, transposed store -> z [pos,128]
    convtile_k<1,1,4,false,false,false,true,true><<<dim3(16, 2, 32), 256, 0, stream>>>(
        h3, pvw, pvb, z, nullptr, nullptr, nullptr, 512, 1024, 1024, 0, 128);

    // ---- VQ: writes out_q (final fp32), hist, loss, indices ----
    vq_k<<<dim3(512), 256, 0, stream>>>(z, CB, out_q, lossA, hist, ipArr);

    // ---- decoder, per batch-HALF (16 samples); LDS-tiled transpose convs, TT=8 ----
    for (int h = 0; h < 2; ++h) {
        convttile_k<3,8><<<dim3(8, 8, 16), 256, 0, stream>>>(
            out_q + (size_t)h * 2097152, d1w, d1b, d1o, 128, 1024, 512);
        convttile_k<5,8><<<dim3(16, 4, 16), 256, 0, stream>>>(
            d1o, d2w, d2b, d2o, 512, 2048, 256);
        convtile_k<7,1,8,false,false,false,false,false><<<dim3(32, 2, 16), 256, 0, stream>>>(
            d2o, d3w, d3b, out_xrec + (size_t)h * 8388608, nullptr, nullptr, nullptr,
            256, 4096, 4096, 3, 128);
    }

    // ---- behavior head (after decoder: d2o overhangs 2 floats into out_beh) ----
    pool_k<<<dim3(4096), 256, 0, stream>>>(out_q, zp);
    beh_k<<<dim3(1), 256, 0, stream>>>(zp, bh1w, bh1b, bh2w, bh2b, bh3w, bh3b, out_beh);

    // ---- one-hot enc (overwrites enc-region scratch with the real output) ----
    enc_k<<<dim3(65536), 256, 0, stream>>>(ipArr, (float2*)out_enc);

    // ---- loss + perplexity ----
    fin_k<<<dim3(1), 1024, 0, stream>>>(hist, lossA, out_loss, out_perp);
}